// Round 8
// baseline (2150.758 us; speedup 1.0000x reference)
//
#include <hip/hip_runtime.h>
#include <cstdint>
#include <cstddef>

using f16 = _Float16;
typedef __attribute__((ext_vector_type(8))) _Float16 f16x8;
typedef __attribute__((ext_vector_type(4))) float f32x4;
typedef __attribute__((ext_vector_type(16))) float f32x16;

#define DEV __device__ __forceinline__

DEV void gload16(const f16* g, f16* l) {
  __builtin_amdgcn_global_load_lds(
      (const __attribute__((address_space(1))) unsigned int*)g,
      (__attribute__((address_space(3))) unsigned int*)l, 16, 0, 0);
}

// ---------------- weight transform: [co][ci][27] f32 -> [tap][co][ci] f16 ----
__global__ __launch_bounds__(256) void k_wcast(const float* __restrict__ W,
                                               f16* __restrict__ out, int total) {
  __shared__ float raw[256 * 27];
  const int t = threadIdx.x;
  const size_t pb = (size_t)blockIdx.x * 256;
  const float* src = W + pb * 27;
  for (int i = t; i < 256 * 27; i += 256) raw[i] = src[i];
  __syncthreads();
  for (int tap = 0; tap < 27; ++tap)
    out[(size_t)tap * total + pb + t] = (f16)raw[t * 27 + tap];
}

// ---------------- point MLP + scatter-max into vox[b][32768][256] f32 --------
__global__ __launch_bounds__(256) void k_mlp(const float* __restrict__ pc,
    const float* __restrict__ w0, const float* __restrict__ b0,
    const float* __restrict__ w1, const float* __restrict__ b1,
    float* __restrict__ vox) {
  __shared__ float s_x[64][9];
  __shared__ int s_flat[64];
  __shared__ float s_w0[128 * 9];
  __shared__ float s_b0[128];
  __shared__ float s_b1[256];
  __shared__ __align__(16) f16 s_h0[64 * 128];
  const int t = threadIdx.x;
  const int pt0 = blockIdx.x * 64;
  const int b = pt0 >> 15;
  for (int i = t; i < 128 * 9; i += 256) s_w0[i] = w0[i];
  if (t < 128) s_b0[t] = b0[t];
  if (t >= 128) s_b1[t - 128] = b1[t - 128];
  if (t < 128) s_b1[t + 128] = b1[t + 128];
  if (t < 64) {
    const float* p = pc + (size_t)(pt0 + t) * 6;
    float x = p[0], y = p[1], z = p[2];
    int ix = (int)floorf(x * 32.f), iy = (int)floorf(y * 32.f), iz = (int)floorf(z * 32.f);
    float cx = (ix + 0.5f) * 0.03125f, cy = (iy + 0.5f) * 0.03125f, cz = (iz + 0.5f) * 0.03125f;
    s_x[t][0] = x - cx; s_x[t][1] = y - cy; s_x[t][2] = z - cz;
    s_x[t][3] = cx; s_x[t][4] = cy; s_x[t][5] = cz;
    s_x[t][6] = p[3]; s_x[t][7] = p[4]; s_x[t][8] = p[5];
    s_flat[t] = (ix * 32 + iy) * 32 + iz;
  }
  __syncthreads();
  {
    const int pt = t >> 2, o0 = (t & 3) * 32;
    float xr[9];
    #pragma unroll
    for (int i = 0; i < 9; ++i) xr[i] = s_x[pt][i];
    for (int j = 0; j < 32; ++j) {
      const int o = o0 + j;
      float s = s_b0[o];
      #pragma unroll
      for (int i = 0; i < 9; ++i) s += xr[i] * s_w0[o * 9 + i];
      s_h0[pt * 128 + o] = (f16)fmaxf(s, 0.f);
    }
  }
  __syncthreads();
  const int l = t & 63, w = t >> 6;
  const int co0 = w * 64;
  f32x4 acc[4][4] = {};
  #pragma unroll
  for (int kc = 0; kc < 4; ++kc) {
    f16x8 af[4], bf[4];
    #pragma unroll
    for (int mf = 0; mf < 4; ++mf)
      af[mf] = *(const f16x8*)&s_h0[(mf * 16 + (l & 15)) * 128 + kc * 32 + (l >> 4) * 8];
    #pragma unroll
    for (int nf = 0; nf < 4; ++nf) {
      const float* wr = w1 + (size_t)(co0 + nf * 16 + (l & 15)) * 128 + kc * 32 + (l >> 4) * 8;
      f16x8 v;
      #pragma unroll
      for (int i = 0; i < 8; ++i) v[i] = (f16)wr[i];
      bf[nf] = v;
    }
    #pragma unroll
    for (int mf = 0; mf < 4; ++mf)
      #pragma unroll
      for (int nf = 0; nf < 4; ++nf)
        acc[mf][nf] = __builtin_amdgcn_mfma_f32_16x16x32_f16(af[mf], bf[nf], acc[mf][nf], 0, 0, 0);
  }
  unsigned int* vb = (unsigned int*)vox + (size_t)b * 32768 * 256;
  #pragma unroll
  for (int mf = 0; mf < 4; ++mf) {
    #pragma unroll
    for (int r = 0; r < 4; ++r) {
      const int prow = mf * 16 + (l >> 4) * 4 + r;
      const int fl = s_flat[prow];
      #pragma unroll
      for (int nf = 0; nf < 4; ++nf) {
        const int co = co0 + nf * 16 + (l & 15);
        float v = fmaxf(acc[mf][nf][r] + s_b1[co], 0.f);
        atomicMax(&vb[(size_t)fl * 256 + co], __float_as_uint(v));
      }
    }
  }
}

// ---------------- vox f32 -> padded act0 f16 [b][34][34][34][256] ------------
__global__ __launch_bounds__(256) void k_pack(const float* __restrict__ vox, f16* __restrict__ act0) {
  const size_t g = (size_t)blockIdx.x * 256 + threadIdx.x;  // B*32768*32
  const int cg = (int)(g & 31);
  const size_t bv = g >> 5;
  const int v = (int)(bv & 32767);
  const int b = (int)(bv >> 15);
  const int ix = v >> 10, iy = (v >> 5) & 31, iz = v & 31;
  const float* src = vox + bv * 256 + (size_t)cg * 8;
  f16x8 h;
  #pragma unroll
  for (int i = 0; i < 8; ++i) h[i] = (f16)src[i];
  const size_t pad = (size_t)b * 34 * 34 * 34 + (size_t)((ix + 1) * 34 + (iy + 1)) * 34 + (iz + 1);
  *(f16x8*)(act0 + pad * 256 + cg * 8) = h;
}

// ---------------- 8-wave 4-buffer conv3d, 32x32x16 MFMA, counted lgkmcnt -----
// act: [b][S+2][S+2][S+2][CIN] f16 padded ; wt: [27][COUT][CIN] f16
// tile: 256 pos x 256 cout. BK=32 half-steps, 4 LDS buffers (128 KiB),
// prefetch 3 halves ahead, counted vmcnt(8), 1 barrier per half-step.
// Consume: per wave 4x2 frags of 32x32; K=32 as 2 sub-K phases of 8 MFMA,
// lgkmcnt(6) between phases (phase-2 reads land under phase-1 MFMAs).
template<int CIN, int COUT, int S, int TZ, int TY, int TX, int KSPLIT, bool F32OUT>
__global__ __launch_bounds__(512, 2) void k_conv5(
    const f16* __restrict__ act, const f16* __restrict__ wt,
    const float* __restrict__ bias, void* __restrict__ outp) {
  constexpr int SP = S + 2;
  constexpr int CHK = CIN / KSPLIT;
  constexpr int HC = CHK / 32;             // 32-ci halves per tap
  constexpr int NH = 27 * HC;
  constexpr int NXT = S / TX, NYT = S / TY;
  constexpr int NTILES = COUT / 256;
  static_assert(TZ * TY * TX == 256, "M tile must be 256");
  static_assert((HC & (HC - 1)) == 0, "HC pow2");
  __shared__ __align__(16) f16 sm[4 * 16384];  // 128 KiB: [buf][A 16K | B 16K]

  const int t = threadIdx.x, l = t & 63, w = t >> 6;
  const int b = blockIdx.z;
  const int ny = blockIdx.y % NTILES;
  const int chunk = blockIdx.y / NTILES;
  const int co0 = ny * 256;
  int mt = blockIdx.x;
  const int x0 = (mt % NXT) * TX; mt /= NXT;
  const int y0 = (mt % NYT) * TY; mt /= NYT;
  const int z0 = mt * TZ;

  // --- staging: linear LDS dest, inverse-swizzled per-lane global source ---
  const int u = (l & 7) ^ ((l >> 3) & 7);
  const int kun = (u & 3) * 8;
  uint32_t aoff[2], boff[2];
  #pragma unroll
  for (int j = 0; j < 2; ++j) {
    const int row = j * 64 + w * 8 + (l >> 3);   // 0..127
    const int pos = row * 2 + (u >> 2);          // 0..255
    const int tz = pos / (TY * TX), ty = (pos / TX) % TY, tx = pos % TX;
    aoff[j] = (uint32_t)b * (SP * SP * SP * CIN)
            + (uint32_t)(((z0 + tz) * SP + (y0 + ty)) * SP + (x0 + tx)) * CIN
            + (uint32_t)chunk * CHK + kun;
    boff[j] = (uint32_t)(co0 + pos) * CIN + (uint32_t)chunk * CHK + kun;
  }
  const int ldsw = w * 512;

  auto stage = [&](int nbuf, uint32_t sA, uint32_t sB) {
    f16* base = &sm[nbuf * 16384];
    gload16(act + aoff[0] + sA, base + ldsw);
    gload16(act + aoff[1] + sA, base + 4096 + ldsw);
    gload16(wt + boff[0] + sB, base + 8192 + ldsw);
    gload16(wt + boff[1] + sB, base + 12288 + ldsw);
  };

  int kc_ = 0, kw_ = 0, kh_ = 0, kd_ = 0;
  auto nextAB = [&](uint32_t& sA, uint32_t& sB) {
    sA = (uint32_t)(((kd_ * SP + kh_) * SP + kw_) * CIN) + (uint32_t)kc_ * 32;
    sB = (uint32_t)((kd_ * 3 + kh_) * 3 + kw_) * (uint32_t)(COUT * CIN) + (uint32_t)kc_ * 32;
    if (++kc_ == HC) { kc_ = 0; if (++kw_ == 3) { kw_ = 0; if (++kh_ == 3) { kh_ = 0; ++kd_; } } }
  };

  // prologue: stage halves 0,1,2
  {
    uint32_t sA, sB;
    nextAB(sA, sB); stage(0, sA, sB);
    nextAB(sA, sB); stage(1, sA, sB);
    nextAB(sA, sB); stage(2, sA, sB);
  }

  // --- read-side per-lane constants (32x32 fragments) ---
  // A row p = m0 + f*32 + (l&31), ci = kk*16 + (l>>5)*8.  LDS: row-pair rp=p>>1,
  // unit v = (p&1)*4 + kk*2 + (l>>5), stored at v ^ (rp&7); rp&7 == (l>>1)&7.
  const int m0 = (w >> 2) * 128, n0 = (w & 3) * 64;
  const int kb = l >> 5;
  const int sw = (l >> 1) & 7;
  const int rbase = (l & 31) >> 1;
  const int aslot0 = ((((l & 1) << 2) | kb) ^ sw) * 8;            // kk=0
  const int aslot1 = ((((l & 1) << 2) | 2 | kb) ^ sw) * 8;        // kk=1
  const int aidx00 = ((m0 >> 1) + rbase) * 64 + aslot0;
  const int aidx01 = ((m0 >> 1) + rbase) * 64 + aslot1;
  const int bidx00 = 8192 + ((n0 >> 1) + rbase) * 64 + aslot0;
  const int bidx01 = 8192 + ((n0 >> 1) + rbase) * 64 + aslot1;

  f32x16 acc[4][2] = {};

  auto consume = [&](int buf, bool dostage) {
    const int B0 = buf * 16384;
    f16x8 a0[4], a1[4], b0[2], b1[2];
    #pragma unroll
    for (int f = 0; f < 4; ++f) a0[f] = *(const f16x8*)&sm[B0 + aidx00 + f * 1024];
    #pragma unroll
    for (int g = 0; g < 2; ++g) b0[g] = *(const f16x8*)&sm[B0 + bidx00 + g * 1024];
    __builtin_amdgcn_sched_barrier(0);
    #pragma unroll
    for (int f = 0; f < 4; ++f) a1[f] = *(const f16x8*)&sm[B0 + aidx01 + f * 1024];
    #pragma unroll
    for (int g = 0; g < 2; ++g) b1[g] = *(const f16x8*)&sm[B0 + bidx01 + g * 1024];
    if (dostage) { uint32_t sA, sB; nextAB(sA, sB); stage((buf + 3) & 3, sA, sB); }
    __builtin_amdgcn_sched_barrier(0);
    asm volatile("s_waitcnt lgkmcnt(6)" ::: "memory");  // phase-1 frags done
    __builtin_amdgcn_sched_barrier(0);
    __builtin_amdgcn_s_setprio(1);
    #pragma unroll
    for (int f = 0; f < 4; ++f)
      #pragma unroll
      for (int g = 0; g < 2; ++g)
        acc[f][g] = __builtin_amdgcn_mfma_f32_32x32x16_f16(a0[f], b0[g], acc[f][g], 0, 0, 0);
    __builtin_amdgcn_s_setprio(0);
    __builtin_amdgcn_sched_barrier(0);
    asm volatile("s_waitcnt lgkmcnt(0)" ::: "memory");
    __builtin_amdgcn_sched_barrier(0);
    __builtin_amdgcn_s_setprio(1);
    #pragma unroll
    for (int f = 0; f < 4; ++f)
      #pragma unroll
      for (int g = 0; g < 2; ++g)
        acc[f][g] = __builtin_amdgcn_mfma_f32_32x32x16_f16(a1[f], b1[g], acc[f][g], 0, 0, 0);
    __builtin_amdgcn_s_setprio(0);
    __builtin_amdgcn_sched_barrier(0);
  };

  #pragma unroll 4
  for (int h = 0; h < NH - 3; ++h) {
    asm volatile("s_waitcnt vmcnt(8)" ::: "memory");
    __builtin_amdgcn_s_barrier();
    consume(h & 3, true);
  }
  asm volatile("s_waitcnt vmcnt(8)" ::: "memory");
  __builtin_amdgcn_s_barrier();
  consume((NH - 3) & 3, false);
  asm volatile("s_waitcnt vmcnt(4)" ::: "memory");
  __builtin_amdgcn_s_barrier();
  consume((NH - 2) & 3, false);
  asm volatile("s_waitcnt vmcnt(0)" ::: "memory");
  __builtin_amdgcn_s_barrier();
  consume((NH - 1) & 3, false);

  // --- epilogue (32x32 C/D: col = l&31, row = (r&3) + 8*(r>>2) + 4*(l>>5)) ---
  if constexpr (!F32OUT) {
    f16* pp = (f16*)outp;
    float br[2];
    #pragma unroll
    for (int g = 0; g < 2; ++g) br[g] = bias[co0 + n0 + g * 32 + (l & 31)];
    const size_t ppb = (size_t)b * (S * S * S) * COUT;
    #pragma unroll
    for (int f = 0; f < 4; ++f) {
      #pragma unroll
      for (int r = 0; r < 16; ++r) {
        const int p = m0 + f * 32 + (r & 3) + 8 * (r >> 2) + 4 * (l >> 5);
        const int tz = p / (TY * TX), ty = (p / TX) % TY, tx = p % TX;
        const size_t row = ppb + (size_t)(((z0 + tz) * S + (y0 + ty)) * S + (x0 + tx)) * COUT;
        #pragma unroll
        for (int g = 0; g < 2; ++g)
          pp[row + co0 + n0 + g * 32 + (l & 31)] = (f16)fmaxf(acc[f][g][r] + br[g], 0.f);
      }
    }
  } else {
    float* part = (float*)outp;
    const size_t base = ((size_t)chunk * 4 + b) * (S * S * S);
    #pragma unroll
    for (int f = 0; f < 4; ++f) {
      #pragma unroll
      for (int r = 0; r < 16; ++r) {
        const int p = m0 + f * 32 + (r & 3) + 8 * (r >> 2) + 4 * (l >> 5);
        const int tz = p / (TY * TX), ty = (p / TX) % TY, tx = p % TX;
        const int pos = ((z0 + tz) * S + (y0 + ty)) * S + (x0 + tx);
        #pragma unroll
        for (int g = 0; g < 2; ++g)
          part[(base + pos) * COUT + co0 + n0 + g * 32 + (l & 31)] = acc[f][g][r];
      }
    }
  }
}

// ---------------- conv3: same skeleton, tap fixed per block (32x32 MFMA) -----
// act3: [4][6][6][6][2048] f16 padded ; wt: [27][2048][2048] f16
// M = 256 = 4 batches x 64 positions; grid (8 co-tiles, 27 taps); NH = 64.
__global__ __launch_bounds__(512, 2) void k_conv3b(const f16* __restrict__ act,
    const f16* __restrict__ wt, float* __restrict__ part) {
  constexpr int NH = 64;
  __shared__ __align__(16) f16 sm[4 * 16384];

  const int t = threadIdx.x, l = t & 63, w = t >> 6;
  const int co0 = blockIdx.x * 256;
  const int tap = blockIdx.y;
  const int kd = tap / 9, kh = (tap / 3) % 3, kw = tap % 3;

  const int u = (l & 7) ^ ((l >> 3) & 7);
  const int kun = (u & 3) * 8;
  uint32_t aoff[2], boff[2];
  #pragma unroll
  for (int j = 0; j < 2; ++j) {
    const int row = j * 64 + w * 8 + (l >> 3);   // 0..127
    const int pos = row * 2 + (u >> 2);          // 0..255
    const int b = pos >> 6, c = pos & 63;
    const int tz = c >> 4, ty = (c >> 2) & 3, tx = c & 3;
    aoff[j] = (uint32_t)((b * 216 + (tz + kd) * 36 + (ty + kh) * 6 + (tx + kw)) * 2048) + kun;
    boff[j] = (uint32_t)((tap * 2048 + co0 + pos) * 2048) + kun;
  }
  const int ldsw = w * 512;

  auto stage = [&](int nbuf, uint32_t s) {
    f16* base = &sm[nbuf * 16384];
    gload16(act + aoff[0] + s, base + ldsw);
    gload16(act + aoff[1] + s, base + 4096 + ldsw);
    gload16(wt + boff[0] + s, base + 8192 + ldsw);
    gload16(wt + boff[1] + s, base + 12288 + ldsw);
  };

  stage(0, 0); stage(1, 32); stage(2, 64);

  const int m0 = (w >> 2) * 128, n0 = (w & 3) * 64;
  const int kb = l >> 5;
  const int sw = (l >> 1) & 7;
  const int rbase = (l & 31) >> 1;
  const int aslot0 = ((((l & 1) << 2) | kb) ^ sw) * 8;
  const int aslot1 = ((((l & 1) << 2) | 2 | kb) ^ sw) * 8;
  const int aidx00 = ((m0 >> 1) + rbase) * 64 + aslot0;
  const int aidx01 = ((m0 >> 1) + rbase) * 64 + aslot1;
  const int bidx00 = 8192 + ((n0 >> 1) + rbase) * 64 + aslot0;
  const int bidx01 = 8192 + ((n0 >> 1) + rbase) * 64 + aslot1;

  f32x16 acc[4][2] = {};

  auto consume = [&](int buf, int hstage) {
    const int B0 = buf * 16384;
    f16x8 a0[4], a1[4], b0[2], b1[2];
    #pragma unroll
    for (int f = 0; f < 4; ++f) a0[f] = *(const f16x8*)&sm[B0 + aidx00 + f * 1024];
    #pragma unroll
    for (int g = 0; g < 2; ++g) b0[g] = *(const f16x8*)&sm[B0 + bidx00 + g * 1024];
    __builtin_amdgcn_sched_barrier(0);
    #pragma unroll
    for (int f = 0; f < 4; ++f) a1[f] = *(const f16x8*)&sm[B0 + aidx01 + f * 1024];
    #pragma unroll
    for (int g = 0; g < 2; ++g) b1[g] = *(const f16x8*)&sm[B0 + bidx01 + g * 1024];
    if (hstage >= 0) stage((buf + 3) & 3, (uint32_t)hstage * 32u);
    __builtin_amdgcn_sched_barrier(0);
    asm volatile("s_waitcnt lgkmcnt(6)" ::: "memory");
    __builtin_amdgcn_sched_barrier(0);
    __builtin_amdgcn_s_setprio(1);
    #pragma unroll
    for (int f = 0; f < 4; ++f)
      #pragma unroll
      for (int g = 0; g < 2; ++g)
        acc[f][g] = __builtin_amdgcn_mfma_f32_32x32x16_f16(a0[f], b0[g], acc[f][g], 0, 0, 0);
    __builtin_amdgcn_s_setprio(0);
    __builtin_amdgcn_sched_barrier(0);
    asm volatile("s_waitcnt lgkmcnt(0)" ::: "memory");
    __builtin_amdgcn_sched_barrier(0);
    __builtin_amdgcn_s_setprio(1);
    #pragma unroll
    for (int f = 0; f < 4; ++f)
      #pragma unroll
      for (int g = 0; g < 2; ++g)
        acc[f][g] = __builtin_amdgcn_mfma_f32_32x32x16_f16(a1[f], b1[g], acc[f][g], 0, 0, 0);
    __builtin_amdgcn_s_setprio(0);
    __builtin_amdgcn_sched_barrier(0);
  };

  #pragma unroll 4
  for (int h = 0; h < NH - 3; ++h) {
    asm volatile("s_waitcnt vmcnt(8)" ::: "memory");
    __builtin_amdgcn_s_barrier();
    consume(h & 3, h + 3);
  }
  asm volatile("s_waitcnt vmcnt(8)" ::: "memory");
  __builtin_amdgcn_s_barrier();
  consume((NH - 3) & 3, -1);
  asm volatile("s_waitcnt vmcnt(4)" ::: "memory");
  __builtin_amdgcn_s_barrier();
  consume((NH - 2) & 3, -1);
  asm volatile("s_waitcnt vmcnt(0)" ::: "memory");
  __builtin_amdgcn_s_barrier();
  consume((NH - 1) & 3, -1);

  const size_t base = (size_t)tap * 256 * 2048;
  #pragma unroll
  for (int f = 0; f < 4; ++f) {
    #pragma unroll
    for (int r = 0; r < 16; ++r) {
      const int p = m0 + f * 32 + (r & 3) + 8 * (r >> 2) + 4 * (l >> 5);
      #pragma unroll
      for (int g = 0; g < 2; ++g)
        part[base + (size_t)p * 2048 + co0 + n0 + g * 32 + (l & 31)] = acc[f][g][r];
    }
  }
}

// ---------------- maxpool 2x2x2 -> padded next input -------------------------
template<int C, int S>
__global__ __launch_bounds__(256) void k_pool(const f16* __restrict__ pp, f16* __restrict__ an) {
  constexpr int P = S / 2, Q = P + 2, CG = C / 8;
  size_t g = (size_t)blockIdx.x * 256 + threadIdx.x;
  const int cg = (int)(g % CG);
  size_t r = g / CG;
  const int px = (int)(r % P); r /= P;
  const int py = (int)(r % P); r /= P;
  const int pz = (int)(r % P);
  const int b = (int)(r / P);
  float mx[8];
  #pragma unroll
  for (int i = 0; i < 8; ++i) mx[i] = 0.f;  // post-relu inputs are >= 0
  #pragma unroll
  for (int dz = 0; dz < 2; ++dz)
    #pragma unroll
    for (int dy = 0; dy < 2; ++dy)
      #pragma unroll
      for (int dx = 0; dx < 2; ++dx) {
        const size_t v = (size_t)b * S * S * S +
                         (size_t)((2 * pz + dz) * S + (2 * py + dy)) * S + (2 * px + dx);
        const f16x8 x = *(const f16x8*)&pp[v * C + (size_t)cg * 8];
        #pragma unroll
        for (int i = 0; i < 8; ++i) mx[i] = fmaxf(mx[i], (float)x[i]);
      }
  f16x8 o;
  #pragma unroll
  for (int i = 0; i < 8; ++i) o[i] = (f16)mx[i];
  const size_t d = (size_t)b * Q * Q * Q + (size_t)((pz + 1) * Q + (py + 1)) * Q + (px + 1);
  *(f16x8*)&an[d * C + (size_t)cg * 8] = o;
}

// ---------------- conv2 K-split reduce + bias + relu + pool -> act3 padded ---
__global__ __launch_bounds__(256) void k_red2pool(const float* __restrict__ part,
    const float* __restrict__ bias, f16* __restrict__ act3) {
  const int g = blockIdx.x * 256 + threadIdx.x;  // 4*64*256 = 65536
  const int co8 = g & 255;
  const int rest = g >> 8;
  const int px = rest & 3, py = (rest >> 2) & 3, pz = (rest >> 4) & 3, b = rest >> 6;
  float bv[8];
  #pragma unroll
  for (int i = 0; i < 8; ++i) bv[i] = bias[co8 * 8 + i];
  float mx[8];
  #pragma unroll
  for (int i = 0; i < 8; ++i) mx[i] = 0.f;
  #pragma unroll
  for (int dz = 0; dz < 2; ++dz)
    #pragma unroll
    for (int dy = 0; dy < 2; ++dy)
      #pragma unroll
      for (int dx = 0; dx < 2; ++dx) {
        const int pos = ((2 * pz + dz) * 8 + (2 * py + dy)) * 8 + (2 * px + dx);
        float s[8];
        #pragma unroll
        for (int i = 0; i < 8; ++i) s[i] = bv[i];
        for (int c = 0; c < 4; ++c) {
          const float* p = part + ((size_t)(c * 4 + b) * 512 + pos) * 2048 + co8 * 8;
          const f32x4 v0 = *(const f32x4*)p;
          const f32x4 v1 = *(const f32x4*)(p + 4);
          #pragma unroll
          for (int i = 0; i < 4; ++i) { s[i] += v0[i]; s[4 + i] += v1[i]; }
        }
        #pragma unroll
        for (int i = 0; i < 8; ++i) mx[i] = fmaxf(mx[i], s[i]);
      }
  f16x8 o;
  #pragma unroll
  for (int i = 0; i < 8; ++i) o[i] = (f16)mx[i];
  const size_t d = ((size_t)(b * 6 + pz + 1) * 6 + (py + 1)) * 6 + (px + 1);
  *(f16x8*)&act3[d * 2048 + co8 * 8] = o;
}

// ---------------- conv3 reduce + bias + relu + pool -> l4p[b][8][2048] f32 ---
__global__ __launch_bounds__(256) void k_l4fin(const float* __restrict__ part, const float* __restrict__ bias,
                                               float* __restrict__ l4p) {
  const int co = blockIdx.x * 256 + threadIdx.x;  // 0..2047
  const int pp = blockIdx.y;                      // 0..7
  const int b = blockIdx.z;
  const int pz = (pp >> 2) & 1, py = (pp >> 1) & 1, px = pp & 1;
  const float bv = bias[co];
  float mx = 0.f;  // relu'd values are >= 0
  #pragma unroll
  for (int dz = 0; dz < 2; ++dz)
    #pragma unroll
    for (int dy = 0; dy < 2; ++dy)
      #pragma unroll
      for (int dx = 0; dx < 2; ++dx) {
        const int p = b * 64 + ((pz * 2 + dz) << 4) + ((py * 2 + dy) << 2) + (px * 2 + dx);
        float s = bv;
        for (int tp = 0; tp < 27; ++tp) s += part[((size_t)tp * 256 + p) * 2048 + co];
        mx = fmaxf(mx, fmaxf(s, 0.f));
      }
  l4p[((size_t)b * 8 + pp) * 2048 + co] = mx;
}

// ---------------- linear (EMB=16384 -> 128) ----------------------------------
__global__ __launch_bounds__(256) void k_linear(const float* __restrict__ l4p, const float* __restrict__ lw,
                                                const float* __restrict__ lb, float* __restrict__ y) {
  const int o = blockIdx.x, t = threadIdx.x;
  const float* wr = lw + (size_t)o * 16384;
  float a0 = 0, a1 = 0, a2 = 0, a3 = 0;
  for (int k = t; k < 16384; k += 256) {
    const float wv = wr[k];
    const int co = k >> 3, pp = k & 7;
    a0 += wv * l4p[(size_t)(0 * 8 + pp) * 2048 + co];
    a1 += wv * l4p[(size_t)(1 * 8 + pp) * 2048 + co];
    a2 += wv * l4p[(size_t)(2 * 8 + pp) * 2048 + co];
    a3 += wv * l4p[(size_t)(3 * 8 + pp) * 2048 + co];
  }
  __shared__ float red[4][256];
  red[0][t] = a0; red[1][t] = a1; red[2][t] = a2; red[3][t] = a3;
  __syncthreads();
  if (t < 4) {
    float s = 0.f;
    for (int i = 0; i < 256; ++i) s += red[t][i];
    y[t * 128 + o] = s + lb[o];
  }
}

// ---------------- batchnorm over batch (B=4) ---------------------------------
__global__ void k_bn(const float* __restrict__ y, const float* __restrict__ gamma,
                     const float* __restrict__ beta, float* __restrict__ out) {
  const int o = threadIdx.x;  // 128
  const float v0 = y[o], v1 = y[128 + o], v2 = y[256 + o], v3 = y[384 + o];
  const float mu = 0.25f * (v0 + v1 + v2 + v3);
  const float d0 = v0 - mu, d1 = v1 - mu, d2 = v2 - mu, d3 = v3 - mu;
  const float var = 0.25f * (d0 * d0 + d1 * d1 + d2 * d2 + d3 * d3);
  const float inv = 1.0f / sqrtf(var + 1e-5f);
  const float g = gamma[o], be = beta[o];
  out[o] = g * d0 * inv + be;
  out[128 + o] = g * d1 * inv + be;
  out[256 + o] = g * d2 * inv + be;
  out[384 + o] = g * d3 * inv + be;
}

extern "C" void kernel_launch(void* const* d_in, const int* in_sizes, int n_in,
                              void* d_out, int out_size, void* d_ws, size_t ws_size,
                              hipStream_t stream) {
  (void)in_sizes; (void)n_in; (void)out_size; (void)ws_size;
  const float* scene = (const float*)d_in[0];
  const float* pw0 = (const float*)d_in[1];
  const float* pb0 = (const float*)d_in[2];
  const float* pw1 = (const float*)d_in[3];
  const float* pb1 = (const float*)d_in[4];
  const float* cw0 = (const float*)d_in[5];
  const float* cb0 = (const float*)d_in[6];
  const float* cw1 = (const float*)d_in[7];
  const float* cb1 = (const float*)d_in[8];
  const float* cw2 = (const float*)d_in[9];
  const float* cb2 = (const float*)d_in[10];
  const float* cw3 = (const float*)d_in[11];
  const float* cb3 = (const float*)d_in[12];
  const float* lw = (const float*)d_in[13];
  const float* lb = (const float*)d_in[14];
  const float* gm = (const float*)d_in[15];
  const float* bt = (const float*)d_in[16];

  char* ws = (char*)d_ws;
  size_t off = 0;
  auto alloc = [&](size_t bytes) -> char* {
    char* p = ws + off;
    off += (bytes + 255) & ~(size_t)255;
    return p;
  };
  f16* wt0 = (f16*)alloc((size_t)27 * 512 * 256 * 2);
  f16* wt1 = (f16*)alloc((size_t)27 * 1024 * 512 * 2);
  f16* wt2 = (f16*)alloc((size_t)27 * 2048 * 1024 * 2);
  f16* wt3 = (f16*)alloc((size_t)27 * 2048 * 2048 * 2);
  char* arenaA = alloc((size_t)4 * 32768 * 256 * 4);        // 128 MiB
  char* arenaB = alloc((size_t)4 * 34 * 34 * 34 * 256 * 2); // 76.8 MiB
  f16* act1 = (f16*)alloc((size_t)4 * 18 * 18 * 18 * 512 * 2);
  f16* act2 = (f16*)alloc((size_t)4 * 10 * 10 * 10 * 1024 * 2);
  f16* act3 = (f16*)alloc((size_t)4 * 6 * 6 * 6 * 2048 * 2);
  float* l4p = (float*)alloc((size_t)4 * 8 * 2048 * 4);
  float* ybuf = (float*)alloc(512 * 4);

  float* vox = (float*)arenaA;              // live: mlp..pack
  f16* pp0 = (f16*)arenaA;                  // live: conv0..pool0 (vox dead)
  float* part3 = (float*)arenaA;            // live: conv3..l4fin (pp0 dead), 56.6 MB
  f16* act0 = (f16*)arenaB;                 // live: pack..conv0
  f16* pp1 = (f16*)arenaB;                  // live: conv1..pool1 (act0 dead)
  float* part2 = (float*)arenaB;            // live: conv2..red2pool (pp1 dead), 67.1 MB

  hipMemsetAsync(vox, 0, (size_t)4 * 32768 * 256 * 4, stream);
  hipMemsetAsync(act0, 0, (size_t)4 * 34 * 34 * 34 * 256 * 2, stream);
  hipMemsetAsync(act1, 0, (size_t)4 * 18 * 18 * 18 * 512 * 2, stream);
  hipMemsetAsync(act2, 0, (size_t)4 * 10 * 10 * 10 * 1024 * 2, stream);
  hipMemsetAsync(act3, 0, (size_t)4 * 6 * 6 * 6 * 2048 * 2, stream);

  k_wcast<<<512, 256, 0, stream>>>(cw0, wt0, 512 * 256);
  k_wcast<<<2048, 256, 0, stream>>>(cw1, wt1, 1024 * 512);
  k_wcast<<<8192, 256, 0, stream>>>(cw2, wt2, 2048 * 1024);
  k_wcast<<<16384, 256, 0, stream>>>(cw3, wt3, 2048 * 2048);

  k_mlp<<<2048, 256, 0, stream>>>(scene, pw0, pb0, pw1, pb1, vox);
  k_pack<<<16384, 256, 0, stream>>>(vox, act0);

  // conv0/conv1/conv2: unified 4-buffer deep pipeline, 32x32x16 MFMA
  k_conv5<256, 512, 32, 1, 8, 32, 1, false><<<dim3(128, 2, 4), 512, 0, stream>>>(act0, wt0, cb0, pp0);
  k_pool<512, 32><<<4096, 256, 0, stream>>>(pp0, act1);

  k_conv5<512, 1024, 16, 1, 16, 16, 1, false><<<dim3(16, 4, 4), 512, 0, stream>>>(act1, wt1, cb1, pp1);
  k_pool<1024, 16><<<1024, 256, 0, stream>>>(pp1, act2);

  k_conv5<1024, 2048, 8, 4, 8, 8, 4, true><<<dim3(2, 32, 4), 512, 0, stream>>>(act2, wt2, nullptr, part2);
  k_red2pool<<<256, 256, 0, stream>>>(part2, cb2, act3);

  // conv3: deep-pipelined tap-split, 32x32x16 MFMA
  k_conv3b<<<dim3(8, 27), 512, 0, stream>>>(act3, wt3, part3);
  k_l4fin<<<dim3(8, 8, 4), 256, 0, stream>>>(part3, cb3, l4p);

  k_linear<<<128, 256, 0, stream>>>(l4p, lw, lb, ybuf);
  k_bn<<<1, 128, 0, stream>>>(ybuf, gm, bt, (float*)d_out);
}

// Round 9
// 2003.916 us; speedup vs baseline: 1.0733x; 1.0733x over previous
//
#include <hip/hip_runtime.h>
#include <cstdint>
#include <cstddef>

using f16 = _Float16;
typedef __attribute__((ext_vector_type(2))) _Float16 f16x2;
typedef __attribute__((ext_vector_type(8))) _Float16 f16x8;
typedef __attribute__((ext_vector_type(4))) float f32x4;

#define DEV __device__ __forceinline__

DEV void gload16(const f16* g, f16* l) {
  __builtin_amdgcn_global_load_lds(
      (const __attribute__((address_space(1))) unsigned int*)g,
      (__attribute__((address_space(3))) unsigned int*)l, 16, 0, 0);
}

// ------- weight transform: [co][ci][27] f32 -> [tap][co*ci] f16, f16x2 stores
__global__ __launch_bounds__(256) void k_wcast2(const float* __restrict__ W,
                                                f16* __restrict__ out, int total) {
  __shared__ float raw[256 * 55];  // 512 pos, pair-padded (2*27+1)
  const int t = threadIdx.x;
  const size_t pb = (size_t)blockIdx.x * 512;
  const float* src = W + pb * 27;
  for (int i = t; i < 512 * 27; i += 256) {
    const int pos = i / 27, tap = i - pos * 27;
    raw[(pos >> 1) * 55 + (pos & 1) * 27 + tap] = src[i];
  }
  __syncthreads();
  #pragma unroll
  for (int tap = 0; tap < 27; ++tap) {
    f16x2 v;
    v[0] = (f16)raw[t * 55 + tap];
    v[1] = (f16)raw[t * 55 + 27 + tap];
    *(f16x2*)(out + (size_t)tap * total + pb + t * 2) = v;
  }
}

// ---------------- point MLP + scatter-max into vox[b][32768][256] f32 --------
__global__ __launch_bounds__(256) void k_mlp(const float* __restrict__ pc,
    const float* __restrict__ w0, const float* __restrict__ b0,
    const float* __restrict__ w1, const float* __restrict__ b1,
    float* __restrict__ vox) {
  __shared__ float s_x[64][9];
  __shared__ int s_flat[64];
  __shared__ float s_w0[128 * 9];
  __shared__ float s_b0[128];
  __shared__ float s_b1[256];
  __shared__ __align__(16) f16 s_h0[64 * 128];
  const int t = threadIdx.x;
  const int pt0 = blockIdx.x * 64;
  const int b = pt0 >> 15;
  for (int i = t; i < 128 * 9; i += 256) s_w0[i] = w0[i];
  if (t < 128) s_b0[t] = b0[t];
  if (t >= 128) s_b1[t - 128] = b1[t - 128];
  if (t < 128) s_b1[t + 128] = b1[t + 128];
  if (t < 64) {
    const float* p = pc + (size_t)(pt0 + t) * 6;
    float x = p[0], y = p[1], z = p[2];
    int ix = (int)floorf(x * 32.f), iy = (int)floorf(y * 32.f), iz = (int)floorf(z * 32.f);
    float cx = (ix + 0.5f) * 0.03125f, cy = (iy + 0.5f) * 0.03125f, cz = (iz + 0.5f) * 0.03125f;
    s_x[t][0] = x - cx; s_x[t][1] = y - cy; s_x[t][2] = z - cz;
    s_x[t][3] = cx; s_x[t][4] = cy; s_x[t][5] = cz;
    s_x[t][6] = p[3]; s_x[t][7] = p[4]; s_x[t][8] = p[5];
    s_flat[t] = (ix * 32 + iy) * 32 + iz;
  }
  __syncthreads();
  {
    const int pt = t >> 2, o0 = (t & 3) * 32;
    float xr[9];
    #pragma unroll
    for (int i = 0; i < 9; ++i) xr[i] = s_x[pt][i];
    for (int j = 0; j < 32; ++j) {
      const int o = o0 + j;
      float s = s_b0[o];
      #pragma unroll
      for (int i = 0; i < 9; ++i) s += xr[i] * s_w0[o * 9 + i];
      s_h0[pt * 128 + o] = (f16)fmaxf(s, 0.f);
    }
  }
  __syncthreads();
  const int l = t & 63, w = t >> 6;
  const int co0 = w * 64;
  f32x4 acc[4][4] = {};
  #pragma unroll
  for (int kc = 0; kc < 4; ++kc) {
    f16x8 af[4], bf[4];
    #pragma unroll
    for (int mf = 0; mf < 4; ++mf)
      af[mf] = *(const f16x8*)&s_h0[(mf * 16 + (l & 15)) * 128 + kc * 32 + (l >> 4) * 8];
    #pragma unroll
    for (int nf = 0; nf < 4; ++nf) {
      const float* wr = w1 + (size_t)(co0 + nf * 16 + (l & 15)) * 128 + kc * 32 + (l >> 4) * 8;
      f16x8 v;
      #pragma unroll
      for (int i = 0; i < 8; ++i) v[i] = (f16)wr[i];
      bf[nf] = v;
    }
    #pragma unroll
    for (int mf = 0; mf < 4; ++mf)
      #pragma unroll
      for (int nf = 0; nf < 4; ++nf)
        acc[mf][nf] = __builtin_amdgcn_mfma_f32_16x16x32_f16(af[mf], bf[nf], acc[mf][nf], 0, 0, 0);
  }
  unsigned int* vb = (unsigned int*)vox + (size_t)b * 32768 * 256;
  #pragma unroll
  for (int mf = 0; mf < 4; ++mf) {
    #pragma unroll
    for (int r = 0; r < 4; ++r) {
      const int prow = mf * 16 + (l >> 4) * 4 + r;
      const int fl = s_flat[prow];
      #pragma unroll
      for (int nf = 0; nf < 4; ++nf) {
        const int co = co0 + nf * 16 + (l & 15);
        float v = fmaxf(acc[mf][nf][r] + s_b1[co], 0.f);
        atomicMax(&vb[(size_t)fl * 256 + co], __float_as_uint(v));
      }
    }
  }
}

// ---------------- vox f32 -> padded act0 f16 [b][34][34][34][256] ------------
__global__ __launch_bounds__(256) void k_pack(const float* __restrict__ vox, f16* __restrict__ act0) {
  const size_t g = (size_t)blockIdx.x * 256 + threadIdx.x;  // B*32768*32
  const int cg = (int)(g & 31);
  const size_t bv = g >> 5;
  const int v = (int)(bv & 32767);
  const int b = (int)(bv >> 15);
  const int ix = v >> 10, iy = (v >> 5) & 31, iz = v & 31;
  const float* src = vox + bv * 256 + (size_t)cg * 8;
  f16x8 h;
  #pragma unroll
  for (int i = 0; i < 8; ++i) h[i] = (f16)src[i];
  const size_t pad = (size_t)b * 34 * 34 * 34 + (size_t)((ix + 1) * 34 + (iy + 1)) * 34 + (iz + 1);
  *(f16x8*)(act0 + pad * 256 + cg * 8) = h;
}

// ---------------- 8-wave 4-buffer conv3d, 2-phase consume, counted lgkmcnt ---
// act: [b][S+2][S+2][S+2][CIN] f16 padded ; wt: [27][COUT][CIN] f16
// tile: 256 pos x 256 cout. BK=32 half-steps, 4 LDS buffers (128 KiB),
// prefetch 3 halves ahead, counted vmcnt(8), 1 barrier per half-step.
template<int CIN, int COUT, int S, int TZ, int TY, int TX, int KSPLIT, bool F32OUT>
__global__ __launch_bounds__(512, 2) void k_conv5(
    const f16* __restrict__ act, const f16* __restrict__ wt,
    const float* __restrict__ bias, void* __restrict__ outp) {
  constexpr int SP = S + 2;
  constexpr int CHK = CIN / KSPLIT;
  constexpr int HC = CHK / 32;             // 32-ci halves per tap
  constexpr int NH = 27 * HC;
  constexpr int NXT = S / TX, NYT = S / TY;
  constexpr int NTILES = COUT / 256;
  static_assert(TZ * TY * TX == 256, "M tile must be 256");
  static_assert((HC & (HC - 1)) == 0, "HC pow2");
  __shared__ __align__(16) f16 sm[4 * 16384];  // 128 KiB: [buf][A 16K | B 16K]

  const int t = threadIdx.x, l = t & 63, w = t >> 6;
  const int b = blockIdx.z;
  const int ny = blockIdx.y % NTILES;
  const int chunk = blockIdx.y / NTILES;
  const int co0 = ny * 256;
  int mt = blockIdx.x;
  const int x0 = (mt % NXT) * TX; mt /= NXT;
  const int y0 = (mt % NYT) * TY; mt /= NYT;
  const int z0 = mt * TZ;

  // --- staging: linear LDS dest, inverse-swizzled per-lane global source ---
  const int u = (l & 7) ^ ((l >> 3) & 7);
  const int kun = (u & 3) * 8;
  uint32_t aoff[2], boff[2];
  #pragma unroll
  for (int j = 0; j < 2; ++j) {
    const int row = j * 64 + w * 8 + (l >> 3);   // 0..127
    const int pos = row * 2 + (u >> 2);          // 0..255
    const int tz = pos / (TY * TX), ty = (pos / TX) % TY, tx = pos % TX;
    aoff[j] = (uint32_t)b * (SP * SP * SP * CIN)
            + (uint32_t)(((z0 + tz) * SP + (y0 + ty)) * SP + (x0 + tx)) * CIN
            + (uint32_t)chunk * CHK + kun;
    boff[j] = (uint32_t)(co0 + pos) * CIN + (uint32_t)chunk * CHK + kun;
  }
  const int ldsw = w * 512;

  auto stage = [&](int nbuf, uint32_t sA, uint32_t sB) {
    f16* base = &sm[nbuf * 16384];
    gload16(act + aoff[0] + sA, base + ldsw);
    gload16(act + aoff[1] + sA, base + 4096 + ldsw);
    gload16(wt + boff[0] + sB, base + 8192 + ldsw);
    gload16(wt + boff[1] + sB, base + 12288 + ldsw);
  };

  int kc_ = 0, kw_ = 0, kh_ = 0, kd_ = 0;
  auto nextAB = [&](uint32_t& sA, uint32_t& sB) {
    sA = (uint32_t)(((kd_ * SP + kh_) * SP + kw_) * CIN) + (uint32_t)kc_ * 32;
    sB = (uint32_t)((kd_ * 3 + kh_) * 3 + kw_) * (uint32_t)(COUT * CIN) + (uint32_t)kc_ * 32;
    if (++kc_ == HC) { kc_ = 0; if (++kw_ == 3) { kw_ = 0; if (++kh_ == 3) { kh_ = 0; ++kd_; } } }
  };

  // prologue: stage halves 0,1,2
  {
    uint32_t sA, sB;
    nextAB(sA, sB); stage(0, sA, sB);
    nextAB(sA, sB); stage(1, sA, sB);
    nextAB(sA, sB); stage(2, sA, sB);
  }

  // --- read-side per-lane constants ---
  const int m0 = (w >> 2) * 128, n0 = (w & 3) * 64;
  const int c0 = l >> 4;
  const int slot = (((l & 1) << 2) | c0) ^ ((l >> 1) & 7);
  const int aidx0 = (m0 / 2 + ((l & 15) >> 1)) * 64 + slot * 8;
  const int bidx0 = 8192 + (n0 / 2 + ((l & 15) >> 1)) * 64 + slot * 8;

  f32x4 acc[8][4] = {};

  auto consume = [&](int buf, bool dostage) {
    const int B0 = buf * 16384;
    f16x8 af0[4], af1[4], bf[4];
    #pragma unroll
    for (int mf = 0; mf < 4; ++mf) af0[mf] = *(const f16x8*)&sm[B0 + aidx0 + mf * 512];
    #pragma unroll
    for (int nf = 0; nf < 4; ++nf) bf[nf] = *(const f16x8*)&sm[B0 + bidx0 + nf * 512];
    __builtin_amdgcn_sched_barrier(0);
    #pragma unroll
    for (int mf = 0; mf < 4; ++mf) af1[mf] = *(const f16x8*)&sm[B0 + aidx0 + (4 + mf) * 512];
    if (dostage) { uint32_t sA, sB; nextAB(sA, sB); stage((buf + 3) & 3, sA, sB); }
    __builtin_amdgcn_sched_barrier(0);
    asm volatile("s_waitcnt lgkmcnt(4)" ::: "memory");  // af0+bf done; af1 in flight
    __builtin_amdgcn_sched_barrier(0);
    __builtin_amdgcn_s_setprio(1);
    #pragma unroll
    for (int mf = 0; mf < 4; ++mf)
      #pragma unroll
      for (int nf = 0; nf < 4; ++nf)
        acc[mf][nf] = __builtin_amdgcn_mfma_f32_16x16x32_f16(af0[mf], bf[nf], acc[mf][nf], 0, 0, 0);
    __builtin_amdgcn_s_setprio(0);
    __builtin_amdgcn_sched_barrier(0);
    asm volatile("s_waitcnt lgkmcnt(0)" ::: "memory");
    __builtin_amdgcn_sched_barrier(0);
    __builtin_amdgcn_s_setprio(1);
    #pragma unroll
    for (int mf = 0; mf < 4; ++mf)
      #pragma unroll
      for (int nf = 0; nf < 4; ++nf)
        acc[4 + mf][nf] = __builtin_amdgcn_mfma_f32_16x16x32_f16(af1[mf], bf[nf], acc[4 + mf][nf], 0, 0, 0);
    __builtin_amdgcn_s_setprio(0);
    __builtin_amdgcn_sched_barrier(0);
  };

  #pragma unroll 4
  for (int h = 0; h < NH - 3; ++h) {
    asm volatile("s_waitcnt vmcnt(8)" ::: "memory");
    __builtin_amdgcn_s_barrier();
    consume(h & 3, true);
  }
  asm volatile("s_waitcnt vmcnt(8)" ::: "memory");
  __builtin_amdgcn_s_barrier();
  consume((NH - 3) & 3, false);
  asm volatile("s_waitcnt vmcnt(4)" ::: "memory");
  __builtin_amdgcn_s_barrier();
  consume((NH - 2) & 3, false);
  asm volatile("s_waitcnt vmcnt(0)" ::: "memory");
  __builtin_amdgcn_s_barrier();
  consume((NH - 1) & 3, false);

  // --- epilogue ---
  if constexpr (!F32OUT) {
    f16* pp = (f16*)outp;
    float br[4];
    #pragma unroll
    for (int nf = 0; nf < 4; ++nf) br[nf] = bias[co0 + n0 + nf * 16 + (l & 15)];
    const size_t ppb = (size_t)b * (S * S * S) * COUT;
    #pragma unroll
    for (int mf = 0; mf < 8; ++mf) {
      #pragma unroll
      for (int r = 0; r < 4; ++r) {
        const int p = m0 + mf * 16 + (l >> 4) * 4 + r;
        const int tz = p / (TY * TX), ty = (p / TX) % TY, tx = p % TX;
        const size_t row = ppb + (size_t)(((z0 + tz) * S + (y0 + ty)) * S + (x0 + tx)) * COUT;
        #pragma unroll
        for (int nf = 0; nf < 4; ++nf)
          pp[row + co0 + n0 + nf * 16 + (l & 15)] = (f16)fmaxf(acc[mf][nf][r] + br[nf], 0.f);
      }
    }
  } else {
    float* part = (float*)outp;
    const size_t base = ((size_t)chunk * 4 + b) * (S * S * S);
    #pragma unroll
    for (int mf = 0; mf < 8; ++mf) {
      #pragma unroll
      for (int r = 0; r < 4; ++r) {
        const int p = m0 + mf * 16 + (l >> 4) * 4 + r;
        const int tz = p / (TY * TX), ty = (p / TX) % TY, tx = p % TX;
        const int pos = ((z0 + tz) * S + (y0 + ty)) * S + (x0 + tx);
        #pragma unroll
        for (int nf = 0; nf < 4; ++nf)
          part[(base + pos) * COUT + co0 + n0 + nf * 16 + (l & 15)] = acc[mf][nf][r];
      }
    }
  }
}

// ---------------- conv3: k_conv5 skeleton, tap fixed per block ---------------
// act3: [4][6][6][6][2048] f16 padded ; wt: [27][2048][2048] f16
// M = 256 = 4 batches x 64 positions; grid (8 co-tiles, 27 taps); NH = 64.
__global__ __launch_bounds__(512, 2) void k_conv3b(const f16* __restrict__ act,
    const f16* __restrict__ wt, float* __restrict__ part) {
  constexpr int NH = 64;
  __shared__ __align__(16) f16 sm[4 * 16384];

  const int t = threadIdx.x, l = t & 63, w = t >> 6;
  const int co0 = blockIdx.x * 256;
  const int tap = blockIdx.y;
  const int kd = tap / 9, kh = (tap / 3) % 3, kw = tap % 3;

  const int u = (l & 7) ^ ((l >> 3) & 7);
  const int kun = (u & 3) * 8;
  uint32_t aoff[2], boff[2];
  #pragma unroll
  for (int j = 0; j < 2; ++j) {
    const int row = j * 64 + w * 8 + (l >> 3);   // 0..127
    const int pos = row * 2 + (u >> 2);          // 0..255
    const int b = pos >> 6, c = pos & 63;
    const int tz = c >> 4, ty = (c >> 2) & 3, tx = c & 3;
    aoff[j] = (uint32_t)((b * 216 + (tz + kd) * 36 + (ty + kh) * 6 + (tx + kw)) * 2048) + kun;
    boff[j] = (uint32_t)((tap * 2048 + co0 + pos) * 2048) + kun;
  }
  const int ldsw = w * 512;

  auto stage = [&](int nbuf, uint32_t s) {
    f16* base = &sm[nbuf * 16384];
    gload16(act + aoff[0] + s, base + ldsw);
    gload16(act + aoff[1] + s, base + 4096 + ldsw);
    gload16(wt + boff[0] + s, base + 8192 + ldsw);
    gload16(wt + boff[1] + s, base + 12288 + ldsw);
  };

  stage(0, 0); stage(1, 32); stage(2, 64);

  const int m0 = (w >> 2) * 128, n0 = (w & 3) * 64;
  const int c0 = l >> 4;
  const int slot = (((l & 1) << 2) | c0) ^ ((l >> 1) & 7);
  const int aidx0 = (m0 / 2 + ((l & 15) >> 1)) * 64 + slot * 8;
  const int bidx0 = 8192 + (n0 / 2 + ((l & 15) >> 1)) * 64 + slot * 8;

  f32x4 acc[8][4] = {};

  auto consume = [&](int buf, int hstage) {
    const int B0 = buf * 16384;
    f16x8 af0[4], af1[4], bf[4];
    #pragma unroll
    for (int mf = 0; mf < 4; ++mf) af0[mf] = *(const f16x8*)&sm[B0 + aidx0 + mf * 512];
    #pragma unroll
    for (int nf = 0; nf < 4; ++nf) bf[nf] = *(const f16x8*)&sm[B0 + bidx0 + nf * 512];
    __builtin_amdgcn_sched_barrier(0);
    #pragma unroll
    for (int mf = 0; mf < 4; ++mf) af1[mf] = *(const f16x8*)&sm[B0 + aidx0 + (4 + mf) * 512];
    if (hstage >= 0) stage((buf + 3) & 3, (uint32_t)hstage * 32u);
    __builtin_amdgcn_sched_barrier(0);
    asm volatile("s_waitcnt lgkmcnt(4)" ::: "memory");
    __builtin_amdgcn_sched_barrier(0);
    __builtin_amdgcn_s_setprio(1);
    #pragma unroll
    for (int mf = 0; mf < 4; ++mf)
      #pragma unroll
      for (int nf = 0; nf < 4; ++nf)
        acc[mf][nf] = __builtin_amdgcn_mfma_f32_16x16x32_f16(af0[mf], bf[nf], acc[mf][nf], 0, 0, 0);
    __builtin_amdgcn_s_setprio(0);
    __builtin_amdgcn_sched_barrier(0);
    asm volatile("s_waitcnt lgkmcnt(0)" ::: "memory");
    __builtin_amdgcn_sched_barrier(0);
    __builtin_amdgcn_s_setprio(1);
    #pragma unroll
    for (int mf = 0; mf < 4; ++mf)
      #pragma unroll
      for (int nf = 0; nf < 4; ++nf)
        acc[4 + mf][nf] = __builtin_amdgcn_mfma_f32_16x16x32_f16(af1[mf], bf[nf], acc[4 + mf][nf], 0, 0, 0);
    __builtin_amdgcn_s_setprio(0);
    __builtin_amdgcn_sched_barrier(0);
  };

  #pragma unroll 4
  for (int h = 0; h < NH - 3; ++h) {
    asm volatile("s_waitcnt vmcnt(8)" ::: "memory");
    __builtin_amdgcn_s_barrier();
    consume(h & 3, h + 3);
  }
  asm volatile("s_waitcnt vmcnt(8)" ::: "memory");
  __builtin_amdgcn_s_barrier();
  consume((NH - 3) & 3, -1);
  asm volatile("s_waitcnt vmcnt(4)" ::: "memory");
  __builtin_amdgcn_s_barrier();
  consume((NH - 2) & 3, -1);
  asm volatile("s_waitcnt vmcnt(0)" ::: "memory");
  __builtin_amdgcn_s_barrier();
  consume((NH - 1) & 3, -1);

  const size_t base = (size_t)tap * 256 * 2048;
  #pragma unroll
  for (int mf = 0; mf < 8; ++mf) {
    #pragma unroll
    for (int r = 0; r < 4; ++r) {
      const int p = m0 + mf * 16 + (l >> 4) * 4 + r;
      #pragma unroll
      for (int nf = 0; nf < 4; ++nf)
        part[base + (size_t)p * 2048 + co0 + n0 + nf * 16 + (l & 15)] = acc[mf][nf][r];
    }
  }
}

// ---------------- maxpool 2x2x2 -> padded next input -------------------------
template<int C, int S>
__global__ __launch_bounds__(256) void k_pool(const f16* __restrict__ pp, f16* __restrict__ an) {
  constexpr int P = S / 2, Q = P + 2, CG = C / 8;
  size_t g = (size_t)blockIdx.x * 256 + threadIdx.x;
  const int cg = (int)(g % CG);
  size_t r = g / CG;
  const int px = (int)(r % P); r /= P;
  const int py = (int)(r % P); r /= P;
  const int pz = (int)(r % P);
  const int b = (int)(r / P);
  float mx[8];
  #pragma unroll
  for (int i = 0; i < 8; ++i) mx[i] = 0.f;  // post-relu inputs are >= 0
  #pragma unroll
  for (int dz = 0; dz < 2; ++dz)
    #pragma unroll
    for (int dy = 0; dy < 2; ++dy)
      #pragma unroll
      for (int dx = 0; dx < 2; ++dx) {
        const size_t v = (size_t)b * S * S * S +
                         (size_t)((2 * pz + dz) * S + (2 * py + dy)) * S + (2 * px + dx);
        const f16x8 x = *(const f16x8*)&pp[v * C + (size_t)cg * 8];
        #pragma unroll
        for (int i = 0; i < 8; ++i) mx[i] = fmaxf(mx[i], (float)x[i]);
      }
  f16x8 o;
  #pragma unroll
  for (int i = 0; i < 8; ++i) o[i] = (f16)mx[i];
  const size_t d = (size_t)b * Q * Q * Q + (size_t)((pz + 1) * Q + (py + 1)) * Q + (px + 1);
  *(f16x8*)&an[d * C + (size_t)cg * 8] = o;
}

// ---------------- conv2 K-split reduce + bias + relu + pool -> act3 padded ---
__global__ __launch_bounds__(256) void k_red2pool(const float* __restrict__ part,
    const float* __restrict__ bias, f16* __restrict__ act3) {
  const int g = blockIdx.x * 256 + threadIdx.x;  // 4*64*256 = 65536
  const int co8 = g & 255;
  const int rest = g >> 8;
  const int px = rest & 3, py = (rest >> 2) & 3, pz = (rest >> 4) & 3, b = rest >> 6;
  float bv[8];
  #pragma unroll
  for (int i = 0; i < 8; ++i) bv[i] = bias[co8 * 8 + i];
  float mx[8];
  #pragma unroll
  for (int i = 0; i < 8; ++i) mx[i] = 0.f;
  #pragma unroll
  for (int dz = 0; dz < 2; ++dz)
    #pragma unroll
    for (int dy = 0; dy < 2; ++dy)
      #pragma unroll
      for (int dx = 0; dx < 2; ++dx) {
        const int pos = ((2 * pz + dz) * 8 + (2 * py + dy)) * 8 + (2 * px + dx);
        float s[8];
        #pragma unroll
        for (int i = 0; i < 8; ++i) s[i] = bv[i];
        for (int c = 0; c < 4; ++c) {
          const float* p = part + ((size_t)(c * 4 + b) * 512 + pos) * 2048 + co8 * 8;
          const f32x4 v0 = *(const f32x4*)p;
          const f32x4 v1 = *(const f32x4*)(p + 4);
          #pragma unroll
          for (int i = 0; i < 4; ++i) { s[i] += v0[i]; s[4 + i] += v1[i]; }
        }
        #pragma unroll
        for (int i = 0; i < 8; ++i) mx[i] = fmaxf(mx[i], s[i]);
      }
  f16x8 o;
  #pragma unroll
  for (int i = 0; i < 8; ++i) o[i] = (f16)mx[i];
  const size_t d = ((size_t)(b * 6 + pz + 1) * 6 + (py + 1)) * 6 + (px + 1);
  *(f16x8*)&act3[d * 2048 + co8 * 8] = o;
}

// ---------------- conv3 reduce + bias + relu + pool -> l4p[b][8][2048] f32 ---
__global__ __launch_bounds__(256) void k_l4fin(const float* __restrict__ part, const float* __restrict__ bias,
                                               float* __restrict__ l4p) {
  const int co = blockIdx.x * 256 + threadIdx.x;  // 0..2047
  const int pp = blockIdx.y;                      // 0..7
  const int b = blockIdx.z;
  const int pz = (pp >> 2) & 1, py = (pp >> 1) & 1, px = pp & 1;
  const float bv = bias[co];
  float mx = 0.f;  // relu'd values are >= 0
  #pragma unroll
  for (int dz = 0; dz < 2; ++dz)
    #pragma unroll
    for (int dy = 0; dy < 2; ++dy)
      #pragma unroll
      for (int dx = 0; dx < 2; ++dx) {
        const int p = b * 64 + ((pz * 2 + dz) << 4) + ((py * 2 + dy) << 2) + (px * 2 + dx);
        float s = bv;
        for (int tp = 0; tp < 27; ++tp) s += part[((size_t)tp * 256 + p) * 2048 + co];
        mx = fmaxf(mx, fmaxf(s, 0.f));
      }
  l4p[((size_t)b * 8 + pp) * 2048 + co] = mx;
}

// ---------------- linear (EMB=16384 -> 128) ----------------------------------
__global__ __launch_bounds__(256) void k_linear(const float* __restrict__ l4p, const float* __restrict__ lw,
                                                const float* __restrict__ lb, float* __restrict__ y) {
  const int o = blockIdx.x, t = threadIdx.x;
  const float* wr = lw + (size_t)o * 16384;
  float a0 = 0, a1 = 0, a2 = 0, a3 = 0;
  for (int k = t; k < 16384; k += 256) {
    const float wv = wr[k];
    const int co = k >> 3, pp = k & 7;
    a0 += wv * l4p[(size_t)(0 * 8 + pp) * 2048 + co];
    a1 += wv * l4p[(size_t)(1 * 8 + pp) * 2048 + co];
    a2 += wv * l4p[(size_t)(2 * 8 + pp) * 2048 + co];
    a3 += wv * l4p[(size_t)(3 * 8 + pp) * 2048 + co];
  }
  __shared__ float red[4][256];
  red[0][t] = a0; red[1][t] = a1; red[2][t] = a2; red[3][t] = a3;
  __syncthreads();
  if (t < 4) {
    float s = 0.f;
    for (int i = 0; i < 256; ++i) s += red[t][i];
    y[t * 128 + o] = s + lb[o];
  }
}

// ---------------- batchnorm over batch (B=4) ---------------------------------
__global__ void k_bn(const float* __restrict__ y, const float* __restrict__ gamma,
                     const float* __restrict__ beta, float* __restrict__ out) {
  const int o = threadIdx.x;  // 128
  const float v0 = y[o], v1 = y[128 + o], v2 = y[256 + o], v3 = y[384 + o];
  const float mu = 0.25f * (v0 + v1 + v2 + v3);
  const float d0 = v0 - mu, d1 = v1 - mu, d2 = v2 - mu, d3 = v3 - mu;
  const float var = 0.25f * (d0 * d0 + d1 * d1 + d2 * d2 + d3 * d3);
  const float inv = 1.0f / sqrtf(var + 1e-5f);
  const float g = gamma[o], be = beta[o];
  out[o] = g * d0 * inv + be;
  out[128 + o] = g * d1 * inv + be;
  out[256 + o] = g * d2 * inv + be;
  out[384 + o] = g * d3 * inv + be;
}

extern "C" void kernel_launch(void* const* d_in, const int* in_sizes, int n_in,
                              void* d_out, int out_size, void* d_ws, size_t ws_size,
                              hipStream_t stream) {
  (void)in_sizes; (void)n_in; (void)out_size; (void)ws_size;
  const float* scene = (const float*)d_in[0];
  const float* pw0 = (const float*)d_in[1];
  const float* pb0 = (const float*)d_in[2];
  const float* pw1 = (const float*)d_in[3];
  const float* pb1 = (const float*)d_in[4];
  const float* cw0 = (const float*)d_in[5];
  const float* cb0 = (const float*)d_in[6];
  const float* cw1 = (const float*)d_in[7];
  const float* cb1 = (const float*)d_in[8];
  const float* cw2 = (const float*)d_in[9];
  const float* cb2 = (const float*)d_in[10];
  const float* cw3 = (const float*)d_in[11];
  const float* cb3 = (const float*)d_in[12];
  const float* lw = (const float*)d_in[13];
  const float* lb = (const float*)d_in[14];
  const float* gm = (const float*)d_in[15];
  const float* bt = (const float*)d_in[16];

  char* ws = (char*)d_ws;
  size_t off = 0;
  auto alloc = [&](size_t bytes) -> char* {
    char* p = ws + off;
    off += (bytes + 255) & ~(size_t)255;
    return p;
  };
  f16* wt0 = (f16*)alloc((size_t)27 * 512 * 256 * 2);
  f16* wt1 = (f16*)alloc((size_t)27 * 1024 * 512 * 2);
  f16* wt2 = (f16*)alloc((size_t)27 * 2048 * 1024 * 2);
  f16* wt3 = (f16*)alloc((size_t)27 * 2048 * 2048 * 2);
  char* arenaA = alloc((size_t)4 * 32768 * 256 * 4);        // 128 MiB
  char* arenaB = alloc((size_t)4 * 34 * 34 * 34 * 256 * 2); // 76.8 MiB
  f16* act1 = (f16*)alloc((size_t)4 * 18 * 18 * 18 * 512 * 2);
  f16* act2 = (f16*)alloc((size_t)4 * 10 * 10 * 10 * 1024 * 2);
  f16* act3 = (f16*)alloc((size_t)4 * 6 * 6 * 6 * 2048 * 2);
  float* l4p = (float*)alloc((size_t)4 * 8 * 2048 * 4);
  float* ybuf = (float*)alloc(512 * 4);

  float* vox = (float*)arenaA;              // live: mlp..pack
  f16* pp0 = (f16*)arenaA;                  // live: conv0..pool0 (vox dead)
  float* part3 = (float*)arenaA;            // live: conv3..l4fin (pp0 dead), 56.6 MB
  f16* act0 = (f16*)arenaB;                 // live: pack..conv0
  f16* pp1 = (f16*)arenaB;                  // live: conv1..pool1 (act0 dead)
  float* part2 = (float*)arenaB;            // live: conv2..red2pool (pp1 dead), 67.1 MB

  hipMemsetAsync(vox, 0, (size_t)4 * 32768 * 256 * 4, stream);
  hipMemsetAsync(act0, 0, (size_t)4 * 34 * 34 * 34 * 256 * 2, stream);
  hipMemsetAsync(act1, 0, (size_t)4 * 18 * 18 * 18 * 512 * 2, stream);
  hipMemsetAsync(act2, 0, (size_t)4 * 10 * 10 * 10 * 1024 * 2, stream);
  hipMemsetAsync(act3, 0, (size_t)4 * 6 * 6 * 6 * 2048 * 2, stream);

  k_wcast2<<<256, 256, 0, stream>>>(cw0, wt0, 512 * 256);
  k_wcast2<<<1024, 256, 0, stream>>>(cw1, wt1, 1024 * 512);
  k_wcast2<<<4096, 256, 0, stream>>>(cw2, wt2, 2048 * 1024);
  k_wcast2<<<8192, 256, 0, stream>>>(cw3, wt3, 2048 * 2048);

  k_mlp<<<2048, 256, 0, stream>>>(scene, pw0, pb0, pw1, pb1, vox);
  k_pack<<<16384, 256, 0, stream>>>(vox, act0);

  // conv0/conv1/conv2: unified 4-buffer deep pipeline (16x16x32 MFMA, R7 form)
  k_conv5<256, 512, 32, 1, 8, 32, 1, false><<<dim3(128, 2, 4), 512, 0, stream>>>(act0, wt0, cb0, pp0);
  k_pool<512, 32><<<4096, 256, 0, stream>>>(pp0, act1);

  k_conv5<512, 1024, 16, 1, 16, 16, 1, false><<<dim3(16, 4, 4), 512, 0, stream>>>(act1, wt1, cb1, pp1);
  k_pool<1024, 16><<<1024, 256, 0, stream>>>(pp1, act2);

  k_conv5<1024, 2048, 8, 4, 8, 8, 4, true><<<dim3(2, 32, 4), 512, 0, stream>>>(act2, wt2, nullptr, part2);
  k_red2pool<<<256, 256, 0, stream>>>(part2, cb2, act3);

  // conv3: deep-pipelined tap-split
  k_conv3b<<<dim3(8, 27), 512, 0, stream>>>(act3, wt3, part3);
  k_l4fin<<<dim3(8, 8, 4), 256, 0, stream>>>(part3, cb3, l4p);

  k_linear<<<128, 256, 0, stream>>>(l4p, lw, lb, ybuf);
  k_bn<<<1, 128, 0, stream>>>(ybuf, gm, bt, (float*)d_out);
}

// Round 10
// 1891.700 us; speedup vs baseline: 1.1369x; 1.0593x over previous
//
#include <hip/hip_runtime.h>
#include <cstdint>
#include <cstddef>

using f16 = _Float16;
typedef __attribute__((ext_vector_type(2))) _Float16 f16x2;
typedef __attribute__((ext_vector_type(8))) _Float16 f16x8;
typedef __attribute__((ext_vector_type(4))) float f32x4;

#define DEV __device__ __forceinline__

DEV void gload16(const f16* g, f16* l) {
  __builtin_amdgcn_global_load_lds(
      (const __attribute__((address_space(1))) unsigned int*)g,
      (__attribute__((address_space(3))) unsigned int*)l, 16, 0, 0);
}

// ------- weight transform: [co][ci][27] f32 -> [tap][co*ci] f16, f16x2 stores
__global__ __launch_bounds__(256) void k_wcast2(const float* __restrict__ W,
                                                f16* __restrict__ out, int total) {
  __shared__ float raw[256 * 55];  // 512 pos, pair-padded (2*27+1)
  const int t = threadIdx.x;
  const size_t pb = (size_t)blockIdx.x * 512;
  const float* src = W + pb * 27;
  for (int i = t; i < 512 * 27; i += 256) {
    const int pos = i / 27, tap = i - pos * 27;
    raw[(pos >> 1) * 55 + (pos & 1) * 27 + tap] = src[i];
  }
  __syncthreads();
  #pragma unroll
  for (int tap = 0; tap < 27; ++tap) {
    f16x2 v;
    v[0] = (f16)raw[t * 55 + tap];
    v[1] = (f16)raw[t * 55 + 27 + tap];
    *(f16x2*)(out + (size_t)tap * total + pb + t * 2) = v;
  }
}

// ---------------- point MLP + scatter-max into vox[b][32768][256] f32 --------
__global__ __launch_bounds__(256) void k_mlp(const float* __restrict__ pc,
    const float* __restrict__ w0, const float* __restrict__ b0,
    const float* __restrict__ w1, const float* __restrict__ b1,
    float* __restrict__ vox) {
  __shared__ float s_x[64][9];
  __shared__ int s_flat[64];
  __shared__ float s_w0[128 * 9];
  __shared__ float s_b0[128];
  __shared__ float s_b1[256];
  __shared__ __align__(16) f16 s_h0[64 * 128];
  const int t = threadIdx.x;
  const int pt0 = blockIdx.x * 64;
  const int b = pt0 >> 15;
  for (int i = t; i < 128 * 9; i += 256) s_w0[i] = w0[i];
  if (t < 128) s_b0[t] = b0[t];
  if (t >= 128) s_b1[t - 128] = b1[t - 128];
  if (t < 128) s_b1[t + 128] = b1[t + 128];
  if (t < 64) {
    const float* p = pc + (size_t)(pt0 + t) * 6;
    float x = p[0], y = p[1], z = p[2];
    int ix = (int)floorf(x * 32.f), iy = (int)floorf(y * 32.f), iz = (int)floorf(z * 32.f);
    float cx = (ix + 0.5f) * 0.03125f, cy = (iy + 0.5f) * 0.03125f, cz = (iz + 0.5f) * 0.03125f;
    s_x[t][0] = x - cx; s_x[t][1] = y - cy; s_x[t][2] = z - cz;
    s_x[t][3] = cx; s_x[t][4] = cy; s_x[t][5] = cz;
    s_x[t][6] = p[3]; s_x[t][7] = p[4]; s_x[t][8] = p[5];
    s_flat[t] = (ix * 32 + iy) * 32 + iz;
  }
  __syncthreads();
  {
    const int pt = t >> 2, o0 = (t & 3) * 32;
    float xr[9];
    #pragma unroll
    for (int i = 0; i < 9; ++i) xr[i] = s_x[pt][i];
    for (int j = 0; j < 32; ++j) {
      const int o = o0 + j;
      float s = s_b0[o];
      #pragma unroll
      for (int i = 0; i < 9; ++i) s += xr[i] * s_w0[o * 9 + i];
      s_h0[pt * 128 + o] = (f16)fmaxf(s, 0.f);
    }
  }
  __syncthreads();
  const int l = t & 63, w = t >> 6;
  const int co0 = w * 64;
  f32x4 acc[4][4] = {};
  #pragma unroll
  for (int kc = 0; kc < 4; ++kc) {
    f16x8 af[4], bf[4];
    #pragma unroll
    for (int mf = 0; mf < 4; ++mf)
      af[mf] = *(const f16x8*)&s_h0[(mf * 16 + (l & 15)) * 128 + kc * 32 + (l >> 4) * 8];
    #pragma unroll
    for (int nf = 0; nf < 4; ++nf) {
      const float* wr = w1 + (size_t)(co0 + nf * 16 + (l & 15)) * 128 + kc * 32 + (l >> 4) * 8;
      f16x8 v;
      #pragma unroll
      for (int i = 0; i < 8; ++i) v[i] = (f16)wr[i];
      bf[nf] = v;
    }
    #pragma unroll
    for (int mf = 0; mf < 4; ++mf)
      #pragma unroll
      for (int nf = 0; nf < 4; ++nf)
        acc[mf][nf] = __builtin_amdgcn_mfma_f32_16x16x32_f16(af[mf], bf[nf], acc[mf][nf], 0, 0, 0);
  }
  unsigned int* vb = (unsigned int*)vox + (size_t)b * 32768 * 256;
  #pragma unroll
  for (int mf = 0; mf < 4; ++mf) {
    #pragma unroll
    for (int r = 0; r < 4; ++r) {
      const int prow = mf * 16 + (l >> 4) * 4 + r;
      const int fl = s_flat[prow];
      #pragma unroll
      for (int nf = 0; nf < 4; ++nf) {
        const int co = co0 + nf * 16 + (l & 15);
        float v = fmaxf(acc[mf][nf][r] + s_b1[co], 0.f);
        atomicMax(&vb[(size_t)fl * 256 + co], __float_as_uint(v));
      }
    }
  }
}

// ---------------- vox f32 -> padded act0 f16 [b][34][34][34][256] ------------
__global__ __launch_bounds__(256) void k_pack(const float* __restrict__ vox, f16* __restrict__ act0) {
  const size_t g = (size_t)blockIdx.x * 256 + threadIdx.x;  // B*32768*32
  const int cg = (int)(g & 31);
  const size_t bv = g >> 5;
  const int v = (int)(bv & 32767);
  const int b = (int)(bv >> 15);
  const int ix = v >> 10, iy = (v >> 5) & 31, iz = v & 31;
  const float* src = vox + bv * 256 + (size_t)cg * 8;
  f16x8 h;
  #pragma unroll
  for (int i = 0; i < 8; ++i) h[i] = (f16)src[i];
  const size_t pad = (size_t)b * 34 * 34 * 34 + (size_t)((ix + 1) * 34 + (iy + 1)) * 34 + (iz + 1);
  *(f16x8*)(act0 + pad * 256 + cg * 8) = h;
}

// ---------------- 8-wave 4-buffer conv3d, 2-phase consume, counted lgkmcnt ---
template<int CIN, int COUT, int S, int TZ, int TY, int TX, int KSPLIT, bool F32OUT>
__global__ __launch_bounds__(512, 2) void k_conv5(
    const f16* __restrict__ act, const f16* __restrict__ wt,
    const float* __restrict__ bias, void* __restrict__ outp) {
  constexpr int SP = S + 2;
  constexpr int CHK = CIN / KSPLIT;
  constexpr int HC = CHK / 32;             // 32-ci halves per tap
  constexpr int NH = 27 * HC;
  constexpr int NXT = S / TX, NYT = S / TY;
  constexpr int NTILES = COUT / 256;
  static_assert(TZ * TY * TX == 256, "M tile must be 256");
  static_assert((HC & (HC - 1)) == 0, "HC pow2");
  __shared__ __align__(16) f16 sm[4 * 16384];  // 128 KiB: [buf][A 16K | B 16K]

  const int t = threadIdx.x, l = t & 63, w = t >> 6;
  const int b = blockIdx.z;
  const int ny = blockIdx.y % NTILES;
  const int chunk = blockIdx.y / NTILES;
  const int co0 = ny * 256;
  int mt = blockIdx.x;
  const int x0 = (mt % NXT) * TX; mt /= NXT;
  const int y0 = (mt % NYT) * TY; mt /= NYT;
  const int z0 = mt * TZ;

  const int u = (l & 7) ^ ((l >> 3) & 7);
  const int kun = (u & 3) * 8;
  uint32_t aoff[2], boff[2];
  #pragma unroll
  for (int j = 0; j < 2; ++j) {
    const int row = j * 64 + w * 8 + (l >> 3);   // 0..127
    const int pos = row * 2 + (u >> 2);          // 0..255
    const int tz = pos / (TY * TX), ty = (pos / TX) % TY, tx = pos % TX;
    aoff[j] = (uint32_t)b * (SP * SP * SP * CIN)
            + (uint32_t)(((z0 + tz) * SP + (y0 + ty)) * SP + (x0 + tx)) * CIN
            + (uint32_t)chunk * CHK + kun;
    boff[j] = (uint32_t)(co0 + pos) * CIN + (uint32_t)chunk * CHK + kun;
  }
  const int ldsw = w * 512;

  auto stage = [&](int nbuf, uint32_t sA, uint32_t sB) {
    f16* base = &sm[nbuf * 16384];
    gload16(act + aoff[0] + sA, base + ldsw);
    gload16(act + aoff[1] + sA, base + 4096 + ldsw);
    gload16(wt + boff[0] + sB, base + 8192 + ldsw);
    gload16(wt + boff[1] + sB, base + 12288 + ldsw);
  };

  int kc_ = 0, kw_ = 0, kh_ = 0, kd_ = 0;
  auto nextAB = [&](uint32_t& sA, uint32_t& sB) {
    sA = (uint32_t)(((kd_ * SP + kh_) * SP + kw_) * CIN) + (uint32_t)kc_ * 32;
    sB = (uint32_t)((kd_ * 3 + kh_) * 3 + kw_) * (uint32_t)(COUT * CIN) + (uint32_t)kc_ * 32;
    if (++kc_ == HC) { kc_ = 0; if (++kw_ == 3) { kw_ = 0; if (++kh_ == 3) { kh_ = 0; ++kd_; } } }
  };

  {
    uint32_t sA, sB;
    nextAB(sA, sB); stage(0, sA, sB);
    nextAB(sA, sB); stage(1, sA, sB);
    nextAB(sA, sB); stage(2, sA, sB);
  }

  const int m0 = (w >> 2) * 128, n0 = (w & 3) * 64;
  const int c0 = l >> 4;
  const int slot = (((l & 1) << 2) | c0) ^ ((l >> 1) & 7);
  const int aidx0 = (m0 / 2 + ((l & 15) >> 1)) * 64 + slot * 8;
  const int bidx0 = 8192 + (n0 / 2 + ((l & 15) >> 1)) * 64 + slot * 8;

  f32x4 acc[8][4] = {};

  auto consume = [&](int buf, bool dostage) {
    const int B0 = buf * 16384;
    f16x8 af0[4], af1[4], bf[4];
    #pragma unroll
    for (int mf = 0; mf < 4; ++mf) af0[mf] = *(const f16x8*)&sm[B0 + aidx0 + mf * 512];
    #pragma unroll
    for (int nf = 0; nf < 4; ++nf) bf[nf] = *(const f16x8*)&sm[B0 + bidx0 + nf * 512];
    __builtin_amdgcn_sched_barrier(0);
    #pragma unroll
    for (int mf = 0; mf < 4; ++mf) af1[mf] = *(const f16x8*)&sm[B0 + aidx0 + (4 + mf) * 512];
    if (dostage) { uint32_t sA, sB; nextAB(sA, sB); stage((buf + 3) & 3, sA, sB); }
    __builtin_amdgcn_sched_barrier(0);
    asm volatile("s_waitcnt lgkmcnt(4)" ::: "memory");
    __builtin_amdgcn_sched_barrier(0);
    __builtin_amdgcn_s_setprio(1);
    #pragma unroll
    for (int mf = 0; mf < 4; ++mf)
      #pragma unroll
      for (int nf = 0; nf < 4; ++nf)
        acc[mf][nf] = __builtin_amdgcn_mfma_f32_16x16x32_f16(af0[mf], bf[nf], acc[mf][nf], 0, 0, 0);
    __builtin_amdgcn_s_setprio(0);
    __builtin_amdgcn_sched_barrier(0);
    asm volatile("s_waitcnt lgkmcnt(0)" ::: "memory");
    __builtin_amdgcn_sched_barrier(0);
    __builtin_amdgcn_s_setprio(1);
    #pragma unroll
    for (int mf = 0; mf < 4; ++mf)
      #pragma unroll
      for (int nf = 0; nf < 4; ++nf)
        acc[4 + mf][nf] = __builtin_amdgcn_mfma_f32_16x16x32_f16(af1[mf], bf[nf], acc[4 + mf][nf], 0, 0, 0);
    __builtin_amdgcn_s_setprio(0);
    __builtin_amdgcn_sched_barrier(0);
  };

  #pragma unroll 4
  for (int h = 0; h < NH - 3; ++h) {
    asm volatile("s_waitcnt vmcnt(8)" ::: "memory");
    __builtin_amdgcn_s_barrier();
    consume(h & 3, true);
  }
  asm volatile("s_waitcnt vmcnt(8)" ::: "memory");
  __builtin_amdgcn_s_barrier();
  consume((NH - 3) & 3, false);
  asm volatile("s_waitcnt vmcnt(4)" ::: "memory");
  __builtin_amdgcn_s_barrier();
  consume((NH - 2) & 3, false);
  asm volatile("s_waitcnt vmcnt(0)" ::: "memory");
  __builtin_amdgcn_s_barrier();
  consume((NH - 1) & 3, false);

  if constexpr (!F32OUT) {
    f16* pp = (f16*)outp;
    float br[4];
    #pragma unroll
    for (int nf = 0; nf < 4; ++nf) br[nf] = bias[co0 + n0 + nf * 16 + (l & 15)];
    const size_t ppb = (size_t)b * (S * S * S) * COUT;
    #pragma unroll
    for (int mf = 0; mf < 8; ++mf) {
      #pragma unroll
      for (int r = 0; r < 4; ++r) {
        const int p = m0 + mf * 16 + (l >> 4) * 4 + r;
        const int tz = p / (TY * TX), ty = (p / TX) % TY, tx = p % TX;
        const size_t row = ppb + (size_t)(((z0 + tz) * S + (y0 + ty)) * S + (x0 + tx)) * COUT;
        #pragma unroll
        for (int nf = 0; nf < 4; ++nf)
          pp[row + co0 + n0 + nf * 16 + (l & 15)] = (f16)fmaxf(acc[mf][nf][r] + br[nf], 0.f);
      }
    }
  } else {
    float* part = (float*)outp;
    const size_t base = ((size_t)chunk * 4 + b) * (S * S * S);
    #pragma unroll
    for (int mf = 0; mf < 8; ++mf) {
      #pragma unroll
      for (int r = 0; r < 4; ++r) {
        const int p = m0 + mf * 16 + (l >> 4) * 4 + r;
        const int tz = p / (TY * TX), ty = (p / TX) % TY, tx = p % TX;
        const int pos = ((z0 + tz) * S + (y0 + ty)) * S + (x0 + tx);
        #pragma unroll
        for (int nf = 0; nf < 4; ++nf)
          part[(base + pos) * COUT + co0 + n0 + nf * 16 + (l & 15)] = acc[mf][nf][r];
      }
    }
  }
}

// ---------------- im2col for conv3: act3 -> A3[256 pos][55296 K] f16 ---------
// K = ci*27 + tap (matches f32 weight layout [co][ci][27] flattened).
__global__ __launch_bounds__(256) void k_im2col(const f16* __restrict__ act3,
                                                f16* __restrict__ A3) {
  const int g = blockIdx.x * 256 + threadIdx.x;  // 256*2048 = 524288
  const int ci = g & 2047;
  const int pos = g >> 11;
  const int b = pos >> 6, c = pos & 63;
  const int tz = c >> 4, ty = (c >> 2) & 3, tx = c & 3;
  f16* dst = A3 + (size_t)pos * 55296 + ci * 27;
  #pragma unroll
  for (int kd = 0; kd < 3; ++kd)
    #pragma unroll
    for (int kh = 0; kh < 3; ++kh)
      #pragma unroll
      for (int kw = 0; kw < 3; ++kw)
        dst[(kd * 3 + kh) * 3 + kw] =
            act3[(size_t)((b * 216 + (tz + kd) * 36 + (ty + kh) * 6 + (tx + kw)) * 2048) + ci];
}

// ---------------- conv3c: GEMM 256x2048 @ K=55296, B direct from f32 weights -
// A3: [256][55296] f16 (im2col); W: [2048][55296] f32 (raw input layout).
// grid (8 co-tiles, 27 K-chunks of 2048); NH = 64 half-steps of K=32.
// A: global_load_lds 3-deep.  B: reg-load f32 3-deep -> cvt -> ds_write.
// Per-step issue order [B x4, A x2] -> steady vmcnt(8).
__global__ __launch_bounds__(512, 2) void k_conv3c(const f16* __restrict__ A3,
    const float* __restrict__ W, float* __restrict__ part) {
  __shared__ __align__(16) f16 sm[4 * 16384];
  const int t = threadIdx.x, l = t & 63, w = t >> 6;
  const int co0 = blockIdx.x * 256;
  const int chunk = blockIdx.y;
  const uint32_t kb0 = (uint32_t)chunk * 2048;

  const int u = (l & 7) ^ ((l >> 3) & 7);
  const int kun = (u & 3) * 8;
  uint32_t aoff[2];
  const float* wrow[2];
  #pragma unroll
  for (int j = 0; j < 2; ++j) {
    const int row = j * 64 + w * 8 + (l >> 3);
    const int pos = row * 2 + (u >> 2);
    aoff[j] = (uint32_t)pos * 55296u + kb0 + kun;
    wrow[j] = W + (size_t)(co0 + pos) * 55296 + kb0 + kun;
  }
  const int ldsw = w * 512;

  auto stageA = [&](int nbuf, uint32_t s) {
    f16* base = &sm[nbuf * 16384];
    gload16(A3 + aoff[0] + s, base + ldsw);
    gload16(A3 + aoff[1] + s, base + 4096 + ldsw);
  };
  f32x4 bregA[4], bregB[4];
  auto loadB = [&](f32x4 (&bs)[4], uint32_t s) {
    bs[0] = *(const f32x4*)(wrow[0] + s);
    bs[1] = *(const f32x4*)(wrow[0] + s + 4);
    bs[2] = *(const f32x4*)(wrow[1] + s);
    bs[3] = *(const f32x4*)(wrow[1] + s + 4);
  };
  auto writeB = [&](int nbuf, const f32x4 (&bs)[4]) {
    f16* base = &sm[nbuf * 16384 + 8192 + ldsw + l * 8];
    f16x8 v0, v1;
    #pragma unroll
    for (int i = 0; i < 4; ++i) {
      v0[i] = (f16)bs[0][i]; v0[4 + i] = (f16)bs[1][i];
      v1[i] = (f16)bs[2][i]; v1[4 + i] = (f16)bs[3][i];
    }
    *(f16x8*)(base) = v0;
    *(f16x8*)(base + 4096) = v1;
  };

  const int m0 = (w >> 2) * 128, n0 = (w & 3) * 64;
  const int c0 = l >> 4;
  const int slot = (((l & 1) << 2) | c0) ^ ((l >> 1) & 7);
  const int aidx0 = (m0 / 2 + ((l & 15) >> 1)) * 64 + slot * 8;
  const int bidx0 = 8192 + (n0 / 2 + ((l & 15) >> 1)) * 64 + slot * 8;

  f32x4 acc[8][4] = {};

  // consume step k: buf=k&3; cvt+write B(k+1) from bs; load B(k+3) into bs and
  // stage A(k+3) when hn>=0.
  auto consume = [&](int buf, f32x4 (&bs)[4], int hn, bool dowrite) {
    if (dowrite) writeB((buf + 1) & 3, bs);
    __builtin_amdgcn_s_barrier();
    const int B0 = buf * 16384;
    f16x8 af0[4], af1[4], bf[4];
    #pragma unroll
    for (int mf = 0; mf < 4; ++mf) af0[mf] = *(const f16x8*)&sm[B0 + aidx0 + mf * 512];
    #pragma unroll
    for (int nf = 0; nf < 4; ++nf) bf[nf] = *(const f16x8*)&sm[B0 + bidx0 + nf * 512];
    __builtin_amdgcn_sched_barrier(0);
    #pragma unroll
    for (int mf = 0; mf < 4; ++mf) af1[mf] = *(const f16x8*)&sm[B0 + aidx0 + (4 + mf) * 512];
    if (hn >= 0) { loadB(bs, (uint32_t)hn * 32u); stageA(hn & 3, (uint32_t)hn * 32u); }
    __builtin_amdgcn_sched_barrier(0);
    asm volatile("s_waitcnt lgkmcnt(4)" ::: "memory");
    __builtin_amdgcn_sched_barrier(0);
    __builtin_amdgcn_s_setprio(1);
    #pragma unroll
    for (int mf = 0; mf < 4; ++mf)
      #pragma unroll
      for (int nf = 0; nf < 4; ++nf)
        acc[mf][nf] = __builtin_amdgcn_mfma_f32_16x16x32_f16(af0[mf], bf[nf], acc[mf][nf], 0, 0, 0);
    __builtin_amdgcn_s_setprio(0);
    __builtin_amdgcn_sched_barrier(0);
    asm volatile("s_waitcnt lgkmcnt(0)" ::: "memory");
    __builtin_amdgcn_sched_barrier(0);
    __builtin_amdgcn_s_setprio(1);
    #pragma unroll
    for (int mf = 0; mf < 4; ++mf)
      #pragma unroll
      for (int nf = 0; nf < 4; ++nf)
        acc[4 + mf][nf] = __builtin_amdgcn_mfma_f32_16x16x32_f16(af1[mf], bf[nf], acc[4 + mf][nf], 0, 0, 0);
    __builtin_amdgcn_s_setprio(0);
    __builtin_amdgcn_sched_barrier(0);
  };

  // prologue: B(0) load+cvt+write; B(1)->bregB, B(2)->bregA; A(0..2) staged.
  loadB(bregA, 0);
  asm volatile("s_waitcnt vmcnt(0)" ::: "memory");
  writeB(0, bregA);
  loadB(bregB, 32);
  loadB(bregA, 64);
  stageA(0, 0); stageA(1, 32); stageA(2, 64);
  asm volatile("s_waitcnt lgkmcnt(0)" ::: "memory");  // writeB(0) visible
  __builtin_amdgcn_sched_barrier(0);

  // step 0: queue [B1,B2,A0,A1,A2] -> need B1,A0 -> vmcnt(4)
  asm volatile("s_waitcnt vmcnt(4)" ::: "memory");
  consume(0, bregB, 3, true);
  // steps 1..60 (steady vmcnt(8)); set parity: step k uses set (k+1)&1
  #pragma unroll 2
  for (int h = 1; h + 1 <= 60; h += 2) {
    asm volatile("s_waitcnt vmcnt(8)" ::: "memory");
    consume(h & 3, bregA, h + 3, true);
    asm volatile("s_waitcnt vmcnt(8)" ::: "memory");
    consume((h + 1) & 3, bregB, h + 4, true);
  }
  // tail: 61 (no issue), 62, 63
  asm volatile("s_waitcnt vmcnt(8)" ::: "memory");
  consume(61 & 3, bregA, -1, true);
  asm volatile("s_waitcnt vmcnt(2)" ::: "memory");
  consume(62 & 3, bregB, -1, true);
  asm volatile("s_waitcnt vmcnt(0)" ::: "memory");
  consume(63 & 3, bregA, -1, false);

  const size_t base = (size_t)chunk * 256 * 2048;
  #pragma unroll
  for (int mf = 0; mf < 8; ++mf) {
    #pragma unroll
    for (int r = 0; r < 4; ++r) {
      const int p = m0 + mf * 16 + (l >> 4) * 4 + r;
      #pragma unroll
      for (int nf = 0; nf < 4; ++nf)
        part[base + (size_t)p * 2048 + co0 + n0 + nf * 16 + (l & 15)] = acc[mf][nf][r];
    }
  }
}

// ---------------- maxpool 2x2x2 -> padded next input -------------------------
template<int C, int S>
__global__ __launch_bounds__(256) void k_pool(const f16* __restrict__ pp, f16* __restrict__ an) {
  constexpr int P = S / 2, Q = P + 2, CG = C / 8;
  size_t g = (size_t)blockIdx.x * 256 + threadIdx.x;
  const int cg = (int)(g % CG);
  size_t r = g / CG;
  const int px = (int)(r % P); r /= P;
  const int py = (int)(r % P); r /= P;
  const int pz = (int)(r % P);
  const int b = (int)(r / P);
  float mx[8];
  #pragma unroll
  for (int i = 0; i < 8; ++i) mx[i] = 0.f;  // post-relu inputs are >= 0
  #pragma unroll
  for (int dz = 0; dz < 2; ++dz)
    #pragma unroll
    for (int dy = 0; dy < 2; ++dy)
      #pragma unroll
      for (int dx = 0; dx < 2; ++dx) {
        const size_t v = (size_t)b * S * S * S +
                         (size_t)((2 * pz + dz) * S + (2 * py + dy)) * S + (2 * px + dx);
        const f16x8 x = *(const f16x8*)&pp[v * C + (size_t)cg * 8];
        #pragma unroll
        for (int i = 0; i < 8; ++i) mx[i] = fmaxf(mx[i], (float)x[i]);
      }
  f16x8 o;
  #pragma unroll
  for (int i = 0; i < 8; ++i) o[i] = (f16)mx[i];
  const size_t d = (size_t)b * Q * Q * Q + (size_t)((pz + 1) * Q + (py + 1)) * Q + (px + 1);
  *(f16x8*)&an[d * C + (size_t)cg * 8] = o;
}

// ---------------- conv2 K-split reduce + bias + relu + pool -> act3 padded ---
__global__ __launch_bounds__(256) void k_red2pool(const float* __restrict__ part,
    const float* __restrict__ bias, f16* __restrict__ act3) {
  const int g = blockIdx.x * 256 + threadIdx.x;  // 4*64*256 = 65536
  const int co8 = g & 255;
  const int rest = g >> 8;
  const int px = rest & 3, py = (rest >> 2) & 3, pz = (rest >> 4) & 3, b = rest >> 6;
  float bv[8];
  #pragma unroll
  for (int i = 0; i < 8; ++i) bv[i] = bias[co8 * 8 + i];
  float mx[8];
  #pragma unroll
  for (int i = 0; i < 8; ++i) mx[i] = 0.f;
  #pragma unroll
  for (int dz = 0; dz < 2; ++dz)
    #pragma unroll
    for (int dy = 0; dy < 2; ++dy)
      #pragma unroll
      for (int dx = 0; dx < 2; ++dx) {
        const int pos = ((2 * pz + dz) * 8 + (2 * py + dy)) * 8 + (2 * px + dx);
        float s[8];
        #pragma unroll
        for (int i = 0; i < 8; ++i) s[i] = bv[i];
        for (int c = 0; c < 4; ++c) {
          const float* p = part + ((size_t)(c * 4 + b) * 512 + pos) * 2048 + co8 * 8;
          const f32x4 v0 = *(const f32x4*)p;
          const f32x4 v1 = *(const f32x4*)(p + 4);
          #pragma unroll
          for (int i = 0; i < 4; ++i) { s[i] += v0[i]; s[4 + i] += v1[i]; }
        }
        #pragma unroll
        for (int i = 0; i < 8; ++i) mx[i] = fmaxf(mx[i], s[i]);
      }
  f16x8 o;
  #pragma unroll
  for (int i = 0; i < 8; ++i) o[i] = (f16)mx[i];
  const size_t d = ((size_t)(b * 6 + pz + 1) * 6 + (py + 1)) * 6 + (px + 1);
  *(f16x8*)&act3[d * 2048 + co8 * 8] = o;
}

// ---------------- conv3 reduce + bias + relu + pool -> l4p[b][8][2048] f32 ---
__global__ __launch_bounds__(256) void k_l4fin(const float* __restrict__ part, const float* __restrict__ bias,
                                               float* __restrict__ l4p) {
  const int co = blockIdx.x * 256 + threadIdx.x;  // 0..2047
  const int pp = blockIdx.y;                      // 0..7
  const int b = blockIdx.z;
  const int pz = (pp >> 2) & 1, py = (pp >> 1) & 1, px = pp & 1;
  const float bv = bias[co];
  float mx = 0.f;  // relu'd values are >= 0
  #pragma unroll
  for (int dz = 0; dz < 2; ++dz)
    #pragma unroll
    for (int dy = 0; dy < 2; ++dy)
      #pragma unroll
      for (int dx = 0; dx < 2; ++dx) {
        const int p = b * 64 + ((pz * 2 + dz) << 4) + ((py * 2 + dy) << 2) + (px * 2 + dx);
        float s = bv;
        for (int tp = 0; tp < 27; ++tp) s += part[((size_t)tp * 256 + p) * 2048 + co];
        mx = fmaxf(mx, fmaxf(s, 0.f));
      }
  l4p[((size_t)b * 8 + pp) * 2048 + co] = mx;
}

// ---------------- linear (EMB=16384 -> 128) ----------------------------------
__global__ __launch_bounds__(256) void k_linear(const float* __restrict__ l4p, const float* __restrict__ lw,
                                                const float* __restrict__ lb, float* __restrict__ y) {
  const int o = blockIdx.x, t = threadIdx.x;
  const float* wr = lw + (size_t)o * 16384;
  float a0 = 0, a1 = 0, a2 = 0, a3 = 0;
  for (int k = t; k < 16384; k += 256) {
    const float wv = wr[k];
    const int co = k >> 3, pp = k & 7;
    a0 += wv * l4p[(size_t)(0 * 8 + pp) * 2048 + co];
    a1 += wv * l4p[(size_t)(1 * 8 + pp) * 2048 + co];
    a2 += wv * l4p[(size_t)(2 * 8 + pp) * 2048 + co];
    a3 += wv * l4p[(size_t)(3 * 8 + pp) * 2048 + co];
  }
  __shared__ float red[4][256];
  red[0][t] = a0; red[1][t] = a1; red[2][t] = a2; red[3][t] = a3;
  __syncthreads();
  if (t < 4) {
    float s = 0.f;
    for (int i = 0; i < 256; ++i) s += red[t][i];
    y[t * 128 + o] = s + lb[o];
  }
}

// ---------------- batchnorm over batch (B=4) ---------------------------------
__global__ void k_bn(const float* __restrict__ y, const float* __restrict__ gamma,
                     const float* __restrict__ beta, float* __restrict__ out) {
  const int o = threadIdx.x;  // 128
  const float v0 = y[o], v1 = y[128 + o], v2 = y[256 + o], v3 = y[384 + o];
  const float mu = 0.25f * (v0 + v1 + v2 + v3);
  const float d0 = v0 - mu, d1 = v1 - mu, d2 = v2 - mu, d3 = v3 - mu;
  const float var = 0.25f * (d0 * d0 + d1 * d1 + d2 * d2 + d3 * d3);
  const float inv = 1.0f / sqrtf(var + 1e-5f);
  const float g = gamma[o], be = beta[o];
  out[o] = g * d0 * inv + be;
  out[128 + o] = g * d1 * inv + be;
  out[256 + o] = g * d2 * inv + be;
  out[384 + o] = g * d3 * inv + be;
}

extern "C" void kernel_launch(void* const* d_in, const int* in_sizes, int n_in,
                              void* d_out, int out_size, void* d_ws, size_t ws_size,
                              hipStream_t stream) {
  (void)in_sizes; (void)n_in; (void)out_size; (void)ws_size;
  const float* scene = (const float*)d_in[0];
  const float* pw0 = (const float*)d_in[1];
  const float* pb0 = (const float*)d_in[2];
  const float* pw1 = (const float*)d_in[3];
  const float* pb1 = (const float*)d_in[4];
  const float* cw0 = (const float*)d_in[5];
  const float* cb0 = (const float*)d_in[6];
  const float* cw1 = (const float*)d_in[7];
  const float* cb1 = (const float*)d_in[8];
  const float* cw2 = (const float*)d_in[9];
  const float* cb2 = (const float*)d_in[10];
  const float* cw3 = (const float*)d_in[11];
  const float* cb3 = (const float*)d_in[12];
  const float* lw = (const float*)d_in[13];
  const float* lb = (const float*)d_in[14];
  const float* gm = (const float*)d_in[15];
  const float* bt = (const float*)d_in[16];

  char* ws = (char*)d_ws;
  size_t off = 0;
  auto alloc = [&](size_t bytes) -> char* {
    char* p = ws + off;
    off += (bytes + 255) & ~(size_t)255;
    return p;
  };
  f16* wt0 = (f16*)alloc((size_t)27 * 512 * 256 * 2);
  f16* wt1 = (f16*)alloc((size_t)27 * 1024 * 512 * 2);
  f16* wt2 = (f16*)alloc((size_t)27 * 2048 * 1024 * 2);
  f16* A3  = (f16*)alloc((size_t)256 * 55296 * 2);          // 28.3 MiB im2col
  char* arenaA = alloc((size_t)4 * 32768 * 256 * 4);        // 128 MiB
  char* arenaB = alloc((size_t)4 * 34 * 34 * 34 * 256 * 2); // 76.8 MiB
  f16* act1 = (f16*)alloc((size_t)4 * 18 * 18 * 18 * 512 * 2);
  f16* act2 = (f16*)alloc((size_t)4 * 10 * 10 * 10 * 1024 * 2);
  f16* act3 = (f16*)alloc((size_t)4 * 6 * 6 * 6 * 2048 * 2);
  float* l4p = (float*)alloc((size_t)4 * 8 * 2048 * 4);
  float* ybuf = (float*)alloc(512 * 4);

  float* vox = (float*)arenaA;              // live: mlp..pack
  f16* pp0 = (f16*)arenaA;                  // live: conv0..pool0 (vox dead)
  float* part3 = (float*)arenaA;            // live: conv3c..l4fin (pp0 dead), 56.6 MB
  f16* act0 = (f16*)arenaB;                 // live: pack..conv0
  f16* pp1 = (f16*)arenaB;                  // live: conv1..pool1 (act0 dead)
  float* part2 = (float*)arenaB;            // live: conv2..red2pool (pp1 dead), 67.1 MB

  hipMemsetAsync(vox, 0, (size_t)4 * 32768 * 256 * 4, stream);
  hipMemsetAsync(act0, 0, (size_t)4 * 34 * 34 * 34 * 256 * 2, stream);
  hipMemsetAsync(act1, 0, (size_t)4 * 18 * 18 * 18 * 512 * 2, stream);
  hipMemsetAsync(act2, 0, (size_t)4 * 10 * 10 * 10 * 1024 * 2, stream);
  hipMemsetAsync(act3, 0, (size_t)4 * 6 * 6 * 6 * 2048 * 2, stream);

  k_wcast2<<<256, 256, 0, stream>>>(cw0, wt0, 512 * 256);
  k_wcast2<<<1024, 256, 0, stream>>>(cw1, wt1, 1024 * 512);
  k_wcast2<<<4096, 256, 0, stream>>>(cw2, wt2, 2048 * 1024);
  // cw3 consumed directly by k_conv3c (no cast pass)

  k_mlp<<<2048, 256, 0, stream>>>(scene, pw0, pb0, pw1, pb1, vox);
  k_pack<<<16384, 256, 0, stream>>>(vox, act0);

  // conv0/conv1/conv2: unified 4-buffer deep pipeline (16x16x32 MFMA)
  k_conv5<256, 512, 32, 1, 8, 32, 1, false><<<dim3(128, 2, 4), 512, 0, stream>>>(act0, wt0, cb0, pp0);
  k_pool<512, 32><<<4096, 256, 0, stream>>>(pp0, act1);

  k_conv5<512, 1024, 16, 1, 16, 16, 1, false><<<dim3(16, 4, 4), 512, 0, stream>>>(act1, wt1, cb1, pp1);
  k_pool<1024, 16><<<1024, 256, 0, stream>>>(pp1, act2);

  k_conv5<1024, 2048, 8, 4, 8, 8, 4, true><<<dim3(2, 32, 4), 512, 0, stream>>>(act2, wt2, nullptr, part2);
  k_red2pool<<<256, 256, 0, stream>>>(part2, cb2, act3);

  // conv3: im2col + direct-f32-weight GEMM (wcast3 eliminated)
  k_im2col<<<2048, 256, 0, stream>>>(act3, A3);
  k_conv3c<<<dim3(8, 27), 512, 0, stream>>>(A3, cw3, part3);
  k_l4fin<<<dim3(8, 8, 4), 256, 0, stream>>>(part3, cb3, l4p);

  k_linear<<<128, 256, 0, stream>>>(l4p, lw, lb, ybuf);
  k_bn<<<1, 128, 0, stream>>>(ybuf, gm, bt, (float*)d_out);
}

// Round 11
// 1872.431 us; speedup vs baseline: 1.1486x; 1.0103x over previous
//
#include <hip/hip_runtime.h>
#include <cstdint>
#include <cstddef>

using f16 = _Float16;
typedef __attribute__((ext_vector_type(2))) _Float16 f16x2;
typedef __attribute__((ext_vector_type(4))) _Float16 f16x4;
typedef __attribute__((ext_vector_type(8))) _Float16 f16x8;
typedef __attribute__((ext_vector_type(4))) float f32x4;

#define DEV __device__ __forceinline__

DEV void gload16(const f16* g, f16* l) {
  __builtin_amdgcn_global_load_lds(
      (const __attribute__((address_space(1))) unsigned int*)g,
      (__attribute__((address_space(3))) unsigned int*)l, 16, 0, 0);
}

// ------- weight transform: [co][ci][27] f32 -> [tap][co*ci] f16, f16x2 stores
__global__ __launch_bounds__(256) void k_wcast2(const float* __restrict__ W,
                                                f16* __restrict__ out, int total) {
  __shared__ float raw[256 * 55];  // 512 pos, pair-padded (2*27+1)
  const int t = threadIdx.x;
  const size_t pb = (size_t)blockIdx.x * 512;
  const float* src = W + pb * 27;
  for (int i = t; i < 512 * 27; i += 256) {
    const int pos = i / 27, tap = i - pos * 27;
    raw[(pos >> 1) * 55 + (pos & 1) * 27 + tap] = src[i];
  }
  __syncthreads();
  #pragma unroll
  for (int tap = 0; tap < 27; ++tap) {
    f16x2 v;
    v[0] = (f16)raw[t * 55 + tap];
    v[1] = (f16)raw[t * 55 + 27 + tap];
    *(f16x2*)(out + (size_t)tap * total + pb + t * 2) = v;
  }
}

// ---------------- point MLP + scatter-max into vox[b][32768][256] f32 --------
__global__ __launch_bounds__(256) void k_mlp(const float* __restrict__ pc,
    const float* __restrict__ w0, const float* __restrict__ b0,
    const float* __restrict__ w1, const float* __restrict__ b1,
    float* __restrict__ vox) {
  __shared__ float s_x[64][9];
  __shared__ int s_flat[64];
  __shared__ float s_w0[128 * 9];
  __shared__ float s_b0[128];
  __shared__ float s_b1[256];
  __shared__ __align__(16) f16 s_h0[64 * 128];
  const int t = threadIdx.x;
  const int pt0 = blockIdx.x * 64;
  const int b = pt0 >> 15;
  for (int i = t; i < 128 * 9; i += 256) s_w0[i] = w0[i];
  if (t < 128) s_b0[t] = b0[t];
  if (t >= 128) s_b1[t - 128] = b1[t - 128];
  if (t < 128) s_b1[t + 128] = b1[t + 128];
  if (t < 64) {
    const float* p = pc + (size_t)(pt0 + t) * 6;
    float x = p[0], y = p[1], z = p[2];
    int ix = (int)floorf(x * 32.f), iy = (int)floorf(y * 32.f), iz = (int)floorf(z * 32.f);
    float cx = (ix + 0.5f) * 0.03125f, cy = (iy + 0.5f) * 0.03125f, cz = (iz + 0.5f) * 0.03125f;
    s_x[t][0] = x - cx; s_x[t][1] = y - cy; s_x[t][2] = z - cz;
    s_x[t][3] = cx; s_x[t][4] = cy; s_x[t][5] = cz;
    s_x[t][6] = p[3]; s_x[t][7] = p[4]; s_x[t][8] = p[5];
    s_flat[t] = (ix * 32 + iy) * 32 + iz;
  }
  __syncthreads();
  {
    const int pt = t >> 2, o0 = (t & 3) * 32;
    float xr[9];
    #pragma unroll
    for (int i = 0; i < 9; ++i) xr[i] = s_x[pt][i];
    for (int j = 0; j < 32; ++j) {
      const int o = o0 + j;
      float s = s_b0[o];
      #pragma unroll
      for (int i = 0; i < 9; ++i) s += xr[i] * s_w0[o * 9 + i];
      s_h0[pt * 128 + o] = (f16)fmaxf(s, 0.f);
    }
  }
  __syncthreads();
  const int l = t & 63, w = t >> 6;
  const int co0 = w * 64;
  f32x4 acc[4][4] = {};
  #pragma unroll
  for (int kc = 0; kc < 4; ++kc) {
    f16x8 af[4], bf[4];
    #pragma unroll
    for (int mf = 0; mf < 4; ++mf)
      af[mf] = *(const f16x8*)&s_h0[(mf * 16 + (l & 15)) * 128 + kc * 32 + (l >> 4) * 8];
    #pragma unroll
    for (int nf = 0; nf < 4; ++nf) {
      const float* wr = w1 + (size_t)(co0 + nf * 16 + (l & 15)) * 128 + kc * 32 + (l >> 4) * 8;
      f16x8 v;
      #pragma unroll
      for (int i = 0; i < 8; ++i) v[i] = (f16)wr[i];
      bf[nf] = v;
    }
    #pragma unroll
    for (int mf = 0; mf < 4; ++mf)
      #pragma unroll
      for (int nf = 0; nf < 4; ++nf)
        acc[mf][nf] = __builtin_amdgcn_mfma_f32_16x16x32_f16(af[mf], bf[nf], acc[mf][nf], 0, 0, 0);
  }
  unsigned int* vb = (unsigned int*)vox + (size_t)b * 32768 * 256;
  #pragma unroll
  for (int mf = 0; mf < 4; ++mf) {
    #pragma unroll
    for (int r = 0; r < 4; ++r) {
      const int prow = mf * 16 + (l >> 4) * 4 + r;
      const int fl = s_flat[prow];
      #pragma unroll
      for (int nf = 0; nf < 4; ++nf) {
        const int co = co0 + nf * 16 + (l & 15);
        float v = fmaxf(acc[mf][nf][r] + s_b1[co], 0.f);
        atomicMax(&vb[(size_t)fl * 256 + co], __float_as_uint(v));
      }
    }
  }
}

// ---------------- vox f32 -> padded act0 f16 [b][34][34][34][256] ------------
__global__ __launch_bounds__(256) void k_pack(const float* __restrict__ vox, f16* __restrict__ act0) {
  const size_t g = (size_t)blockIdx.x * 256 + threadIdx.x;  // B*32768*32
  const int cg = (int)(g & 31);
  const size_t bv = g >> 5;
  const int v = (int)(bv & 32767);
  const int b = (int)(bv >> 15);
  const int ix = v >> 10, iy = (v >> 5) & 31, iz = v & 31;
  const float* src = vox + bv * 256 + (size_t)cg * 8;
  f16x8 h;
  #pragma unroll
  for (int i = 0; i < 8; ++i) h[i] = (f16)src[i];
  const size_t pad = (size_t)b * 34 * 34 * 34 + (size_t)((ix + 1) * 34 + (iy + 1)) * 34 + (iz + 1);
  *(f16x8*)(act0 + pad * 256 + cg * 8) = h;
}

// ---------------- 8-wave 4-buffer conv3d, 2-phase consume, counted lgkmcnt ---
// act: [b][S+2][S+2][S+2][CIN] f16 padded ; wt: [27][COUT][CIN] f16
// POOL: fused bias+relu+maxpool2 epilogue -> padded [b][S/2+2]^3[COUT] f16.
// Requires TZ,TY,TX even (pool groups within M-tile).
template<int CIN, int COUT, int S, int TZ, int TY, int TX, int KSPLIT, bool F32OUT, bool POOL>
__global__ __launch_bounds__(512, 2) void k_conv5(
    const f16* __restrict__ act, const f16* __restrict__ wt,
    const float* __restrict__ bias, void* __restrict__ outp) {
  constexpr int SP = S + 2;
  constexpr int CHK = CIN / KSPLIT;
  constexpr int HC = CHK / 32;             // 32-ci halves per tap
  constexpr int NH = 27 * HC;
  constexpr int NXT = S / TX, NYT = S / TY;
  constexpr int NTILES = COUT / 256;
  static_assert(TZ * TY * TX == 256, "M tile must be 256");
  static_assert((HC & (HC - 1)) == 0, "HC pow2");
  static_assert(!POOL || (!(TZ & 1) && !(TY & 1) && !(TX & 1)), "POOL needs even tile dims");
  __shared__ __align__(16) f16 sm[4 * 16384];  // 128 KiB: [buf][A 16K | B 16K]

  const int t = threadIdx.x, l = t & 63, w = t >> 6;
  const int b = blockIdx.z;
  const int ny = blockIdx.y % NTILES;
  const int chunk = blockIdx.y / NTILES;
  const int co0 = ny * 256;
  int mt = blockIdx.x;
  const int x0 = (mt % NXT) * TX; mt /= NXT;
  const int y0 = (mt % NYT) * TY; mt /= NYT;
  const int z0 = mt * TZ;

  const int u = (l & 7) ^ ((l >> 3) & 7);
  const int kun = (u & 3) * 8;
  uint32_t aoff[2], boff[2];
  #pragma unroll
  for (int j = 0; j < 2; ++j) {
    const int row = j * 64 + w * 8 + (l >> 3);   // 0..127
    const int pos = row * 2 + (u >> 2);          // 0..255
    const int tz = pos / (TY * TX), ty = (pos / TX) % TY, tx = pos % TX;
    aoff[j] = (uint32_t)b * (SP * SP * SP * CIN)
            + (uint32_t)(((z0 + tz) * SP + (y0 + ty)) * SP + (x0 + tx)) * CIN
            + (uint32_t)chunk * CHK + kun;
    boff[j] = (uint32_t)(co0 + pos) * CIN + (uint32_t)chunk * CHK + kun;
  }
  const int ldsw = w * 512;

  auto stage = [&](int nbuf, uint32_t sA, uint32_t sB) {
    f16* base = &sm[nbuf * 16384];
    gload16(act + aoff[0] + sA, base + ldsw);
    gload16(act + aoff[1] + sA, base + 4096 + ldsw);
    gload16(wt + boff[0] + sB, base + 8192 + ldsw);
    gload16(wt + boff[1] + sB, base + 12288 + ldsw);
  };

  int kc_ = 0, kw_ = 0, kh_ = 0, kd_ = 0;
  auto nextAB = [&](uint32_t& sA, uint32_t& sB) {
    sA = (uint32_t)(((kd_ * SP + kh_) * SP + kw_) * CIN) + (uint32_t)kc_ * 32;
    sB = (uint32_t)((kd_ * 3 + kh_) * 3 + kw_) * (uint32_t)(COUT * CIN) + (uint32_t)kc_ * 32;
    if (++kc_ == HC) { kc_ = 0; if (++kw_ == 3) { kw_ = 0; if (++kh_ == 3) { kh_ = 0; ++kd_; } } }
  };

  {
    uint32_t sA, sB;
    nextAB(sA, sB); stage(0, sA, sB);
    nextAB(sA, sB); stage(1, sA, sB);
    nextAB(sA, sB); stage(2, sA, sB);
  }

  const int m0 = (w >> 2) * 128, n0 = (w & 3) * 64;
  const int c0 = l >> 4;
  const int slot = (((l & 1) << 2) | c0) ^ ((l >> 1) & 7);
  const int aidx0 = (m0 / 2 + ((l & 15) >> 1)) * 64 + slot * 8;
  const int bidx0 = 8192 + (n0 / 2 + ((l & 15) >> 1)) * 64 + slot * 8;

  f32x4 acc[8][4] = {};

  auto consume = [&](int buf, bool dostage) {
    const int B0 = buf * 16384;
    f16x8 af0[4], af1[4], bf[4];
    #pragma unroll
    for (int mf = 0; mf < 4; ++mf) af0[mf] = *(const f16x8*)&sm[B0 + aidx0 + mf * 512];
    #pragma unroll
    for (int nf = 0; nf < 4; ++nf) bf[nf] = *(const f16x8*)&sm[B0 + bidx0 + nf * 512];
    __builtin_amdgcn_sched_barrier(0);
    #pragma unroll
    for (int mf = 0; mf < 4; ++mf) af1[mf] = *(const f16x8*)&sm[B0 + aidx0 + (4 + mf) * 512];
    if (dostage) { uint32_t sA, sB; nextAB(sA, sB); stage((buf + 3) & 3, sA, sB); }
    __builtin_amdgcn_sched_barrier(0);
    asm volatile("s_waitcnt lgkmcnt(4)" ::: "memory");
    __builtin_amdgcn_sched_barrier(0);
    __builtin_amdgcn_s_setprio(1);
    #pragma unroll
    for (int mf = 0; mf < 4; ++mf)
      #pragma unroll
      for (int nf = 0; nf < 4; ++nf)
        acc[mf][nf] = __builtin_amdgcn_mfma_f32_16x16x32_f16(af0[mf], bf[nf], acc[mf][nf], 0, 0, 0);
    __builtin_amdgcn_s_setprio(0);
    __builtin_amdgcn_sched_barrier(0);
    asm volatile("s_waitcnt lgkmcnt(0)" ::: "memory");
    __builtin_amdgcn_sched_barrier(0);
    __builtin_amdgcn_s_setprio(1);
    #pragma unroll
    for (int mf = 0; mf < 4; ++mf)
      #pragma unroll
      for (int nf = 0; nf < 4; ++nf)
        acc[4 + mf][nf] = __builtin_amdgcn_mfma_f32_16x16x32_f16(af1[mf], bf[nf], acc[4 + mf][nf], 0, 0, 0);
    __builtin_amdgcn_s_setprio(0);
    __builtin_amdgcn_sched_barrier(0);
  };

  #pragma unroll 4
  for (int h = 0; h < NH - 3; ++h) {
    asm volatile("s_waitcnt vmcnt(8)" ::: "memory");
    __builtin_amdgcn_s_barrier();
    consume(h & 3, true);
  }
  asm volatile("s_waitcnt vmcnt(8)" ::: "memory");
  __builtin_amdgcn_s_barrier();
  consume((NH - 3) & 3, false);
  asm volatile("s_waitcnt vmcnt(4)" ::: "memory");
  __builtin_amdgcn_s_barrier();
  consume((NH - 2) & 3, false);
  asm volatile("s_waitcnt vmcnt(0)" ::: "memory");
  __builtin_amdgcn_s_barrier();
  consume((NH - 1) & 3, false);

  // --- epilogue ---
  if constexpr (POOL) {
    // all LDS reads retired per-wave before consume exit; barrier orders waves
    __builtin_amdgcn_s_barrier();
    // phase 1: relu'd tile -> LDS [co 256][pos 256] f16, 16B-unit XOR swizzle
    const int lco_ = n0 + (l & 15);
    #pragma unroll
    for (int nf = 0; nf < 4; ++nf) {
      const int co = lco_ + nf * 16;
      const float brv = bias[co0 + co];
      const int swz = (((co & 15) ^ ((co >> 4) & 15)) & 15) << 4;
      #pragma unroll
      for (int mf = 0; mf < 8; ++mf) {
        const int p = m0 + mf * 16 + (l >> 4) * 4;
        f16x4 v;
        #pragma unroll
        for (int r = 0; r < 4; ++r) v[r] = (f16)fmaxf(acc[mf][nf][r] + brv, 0.f);
        *(f16x4*)((char*)sm + co * 512 + ((p * 2) ^ swz)) = v;
      }
    }
    asm volatile("s_waitcnt lgkmcnt(0)" ::: "memory");
    __builtin_amdgcn_s_barrier();
    // phase 2: 2x2x2 max, vectorized global store
    constexpr int PY = TY / 2, PX = TX / 2;
    const int q = t >> 4;                 // 0..31 pooled pos in tile
    const int cs = (t & 15) * 16;         // 16-co strip
    const int qz = q / (PY * PX), qy = (q / PX) % PY, qx = q % PX;
    f16x8 o0, o1;
    #pragma unroll
    for (int i = 0; i < 16; ++i) {
      const int co = cs + i;
      const int swz = (((co & 15) ^ ((co >> 4) & 15)) & 15) << 4;
      float m = 0.f;
      #pragma unroll
      for (int dz = 0; dz < 2; ++dz)
        #pragma unroll
        for (int dy = 0; dy < 2; ++dy) {
          const int p = (2 * qz + dz) * (TY * TX) + (2 * qy + dy) * TX + 2 * qx;
          const f16x2 pr = *(const f16x2*)((const char*)sm + co * 512 + ((p * 2) ^ swz));
          m = fmaxf(m, fmaxf((float)pr[0], (float)pr[1]));
        }
      if (i < 8) o0[i] = (f16)m; else o1[i - 8] = (f16)m;
    }
    constexpr int Q = S / 2 + 2;
    const int gz = (z0 >> 1) + qz + 1, gy = (y0 >> 1) + qy + 1, gx = (x0 >> 1) + qx + 1;
    f16* dst = (f16*)outp + ((size_t)b * Q * Q * Q + (size_t)(gz * Q + gy) * Q + gx) * COUT + co0 + cs;
    *(f16x8*)dst = o0;
    *(f16x8*)(dst + 8) = o1;
  } else if constexpr (!F32OUT) {
    f16* pp = (f16*)outp;
    float br[4];
    #pragma unroll
    for (int nf = 0; nf < 4; ++nf) br[nf] = bias[co0 + n0 + nf * 16 + (l & 15)];
    const size_t ppb = (size_t)b * (S * S * S) * COUT;
    #pragma unroll
    for (int mf = 0; mf < 8; ++mf) {
      #pragma unroll
      for (int r = 0; r < 4; ++r) {
        const int p = m0 + mf * 16 + (l >> 4) * 4 + r;
        const int tz = p / (TY * TX), ty = (p / TX) % TY, tx = p % TX;
        const size_t row = ppb + (size_t)(((z0 + tz) * S + (y0 + ty)) * S + (x0 + tx)) * COUT;
        #pragma unroll
        for (int nf = 0; nf < 4; ++nf)
          pp[row + co0 + n0 + nf * 16 + (l & 15)] = (f16)fmaxf(acc[mf][nf][r] + br[nf], 0.f);
      }
    }
  } else {
    float* part = (float*)outp;
    const size_t base = ((size_t)chunk * 4 + b) * (S * S * S);
    #pragma unroll
    for (int mf = 0; mf < 8; ++mf) {
      #pragma unroll
      for (int r = 0; r < 4; ++r) {
        const int p = m0 + mf * 16 + (l >> 4) * 4 + r;
        const int tz = p / (TY * TX), ty = (p / TX) % TY, tx = p % TX;
        const int pos = ((z0 + tz) * S + (y0 + ty)) * S + (x0 + tx);
        #pragma unroll
        for (int nf = 0; nf < 4; ++nf)
          part[(base + pos) * COUT + co0 + n0 + nf * 16 + (l & 15)] = acc[mf][nf][r];
      }
    }
  }
}

// ---------------- im2col for conv3: act3 -> A3[256 pos][55296 K] f16 ---------
__global__ __launch_bounds__(256) void k_im2col(const f16* __restrict__ act3,
                                                f16* __restrict__ A3) {
  const int g = blockIdx.x * 256 + threadIdx.x;  // 256*2048 = 524288
  const int ci = g & 2047;
  const int pos = g >> 11;
  const int b = pos >> 6, c = pos & 63;
  const int tz = c >> 4, ty = (c >> 2) & 3, tx = c & 3;
  f16* dst = A3 + (size_t)pos * 55296 + ci * 27;
  #pragma unroll
  for (int kd = 0; kd < 3; ++kd)
    #pragma unroll
    for (int kh = 0; kh < 3; ++kh)
      #pragma unroll
      for (int kw = 0; kw < 3; ++kw)
        dst[(kd * 3 + kh) * 3 + kw] =
            act3[(size_t)((b * 216 + (tz + kd) * 36 + (ty + kh) * 6 + (tx + kw)) * 2048) + ci];
}

// ---------------- conv3c: GEMM 256x2048 @ K=55296, B direct from f32 weights -
__global__ __launch_bounds__(512, 2) void k_conv3c(const f16* __restrict__ A3,
    const float* __restrict__ W, float* __restrict__ part) {
  __shared__ __align__(16) f16 sm[4 * 16384];
  const int t = threadIdx.x, l = t & 63, w = t >> 6;
  const int co0 = blockIdx.x * 256;
  const int chunk = blockIdx.y;
  const uint32_t kb0 = (uint32_t)chunk * 2048;

  const int u = (l & 7) ^ ((l >> 3) & 7);
  const int kun = (u & 3) * 8;
  uint32_t aoff[2];
  const float* wrow[2];
  #pragma unroll
  for (int j = 0; j < 2; ++j) {
    const int row = j * 64 + w * 8 + (l >> 3);
    const int pos = row * 2 + (u >> 2);
    aoff[j] = (uint32_t)pos * 55296u + kb0 + kun;
    wrow[j] = W + (size_t)(co0 + pos) * 55296 + kb0 + kun;
  }
  const int ldsw = w * 512;

  auto stageA = [&](int nbuf, uint32_t s) {
    f16* base = &sm[nbuf * 16384];
    gload16(A3 + aoff[0] + s, base + ldsw);
    gload16(A3 + aoff[1] + s, base + 4096 + ldsw);
  };
  f32x4 bregA[4], bregB[4];
  auto loadB = [&](f32x4 (&bs)[4], uint32_t s) {
    bs[0] = *(const f32x4*)(wrow[0] + s);
    bs[1] = *(const f32x4*)(wrow[0] + s + 4);
    bs[2] = *(const f32x4*)(wrow[1] + s);
    bs[3] = *(const f32x4*)(wrow[1] + s + 4);
  };
  auto writeB = [&](int nbuf, const f32x4 (&bs)[4]) {
    f16* base = &sm[nbuf * 16384 + 8192 + ldsw + l * 8];
    f16x8 v0, v1;
    #pragma unroll
    for (int i = 0; i < 4; ++i) {
      v0[i] = (f16)bs[0][i]; v0[4 + i] = (f16)bs[1][i];
      v1[i] = (f16)bs[2][i]; v1[4 + i] = (f16)bs[3][i];
    }
    *(f16x8*)(base) = v0;
    *(f16x8*)(base + 4096) = v1;
  };

  const int m0 = (w >> 2) * 128, n0 = (w & 3) * 64;
  const int c0 = l >> 4;
  const int slot = (((l & 1) << 2) | c0) ^ ((l >> 1) & 7);
  const int aidx0 = (m0 / 2 + ((l & 15) >> 1)) * 64 + slot * 8;
  const int bidx0 = 8192 + (n0 / 2 + ((l & 15) >> 1)) * 64 + slot * 8;

  f32x4 acc[8][4] = {};

  auto consume = [&](int buf, f32x4 (&bs)[4], int hn, bool dowrite) {
    if (dowrite) writeB((buf + 1) & 3, bs);
    __builtin_amdgcn_s_barrier();
    const int B0 = buf * 16384;
    f16x8 af0[4], af1[4], bf[4];
    #pragma unroll
    for (int mf = 0; mf < 4; ++mf) af0[mf] = *(const f16x8*)&sm[B0 + aidx0 + mf * 512];
    #pragma unroll
    for (int nf = 0; nf < 4; ++nf) bf[nf] = *(const f16x8*)&sm[B0 + bidx0 + nf * 512];
    __builtin_amdgcn_sched_barrier(0);
    #pragma unroll
    for (int mf = 0; mf < 4; ++mf) af1[mf] = *(const f16x8*)&sm[B0 + aidx0 + (4 + mf) * 512];
    if (hn >= 0) { loadB(bs, (uint32_t)hn * 32u); stageA(hn & 3, (uint32_t)hn * 32u); }
    __builtin_amdgcn_sched_barrier(0);
    asm volatile("s_waitcnt lgkmcnt(4)" ::: "memory");
    __builtin_amdgcn_sched_barrier(0);
    __builtin_amdgcn_s_setprio(1);
    #pragma unroll
    for (int mf = 0; mf < 4; ++mf)
      #pragma unroll
      for (int nf = 0; nf < 4; ++nf)
        acc[mf][nf] = __builtin_amdgcn_mfma_f32_16x16x32_f16(af0[mf], bf[nf], acc[mf][nf], 0, 0, 0);
    __builtin_amdgcn_s_setprio(0);
    __builtin_amdgcn_sched_barrier(0);
    asm volatile("s_waitcnt lgkmcnt(0)" ::: "memory");
    __builtin_amdgcn_sched_barrier(0);
    __builtin_amdgcn_s_setprio(1);
    #pragma unroll
    for (int mf = 0; mf < 4; ++mf)
      #pragma unroll
      for (int nf = 0; nf < 4; ++nf)
        acc[4 + mf][nf] = __builtin_amdgcn_mfma_f32_16x16x32_f16(af1[mf], bf[nf], acc[4 + mf][nf], 0, 0, 0);
    __builtin_amdgcn_s_setprio(0);
    __builtin_amdgcn_sched_barrier(0);
  };

  loadB(bregA, 0);
  asm volatile("s_waitcnt vmcnt(0)" ::: "memory");
  writeB(0, bregA);
  loadB(bregB, 32);
  loadB(bregA, 64);
  stageA(0, 0); stageA(1, 32); stageA(2, 64);
  asm volatile("s_waitcnt lgkmcnt(0)" ::: "memory");
  __builtin_amdgcn_sched_barrier(0);

  asm volatile("s_waitcnt vmcnt(4)" ::: "memory");
  consume(0, bregB, 3, true);
  #pragma unroll 2
  for (int h = 1; h + 1 <= 60; h += 2) {
    asm volatile("s_waitcnt vmcnt(8)" ::: "memory");
    consume(h & 3, bregA, h + 3, true);
    asm volatile("s_waitcnt vmcnt(8)" ::: "memory");
    consume((h + 1) & 3, bregB, h + 4, true);
  }
  asm volatile("s_waitcnt vmcnt(8)" ::: "memory");
  consume(61 & 3, bregA, -1, true);
  asm volatile("s_waitcnt vmcnt(2)" ::: "memory");
  consume(62 & 3, bregB, -1, true);
  asm volatile("s_waitcnt vmcnt(0)" ::: "memory");
  consume(63 & 3, bregA, -1, false);

  const size_t base = (size_t)chunk * 256 * 2048;
  #pragma unroll
  for (int mf = 0; mf < 8; ++mf) {
    #pragma unroll
    for (int r = 0; r < 4; ++r) {
      const int p = m0 + mf * 16 + (l >> 4) * 4 + r;
      #pragma unroll
      for (int nf = 0; nf < 4; ++nf)
        part[base + (size_t)p * 2048 + co0 + n0 + nf * 16 + (l & 15)] = acc[mf][nf][r];
    }
  }
}

// ---------------- conv2 K-split reduce + bias + relu + pool -> act3 padded ---
__global__ __launch_bounds__(256) void k_red2pool(const float* __restrict__ part,
    const float* __restrict__ bias, f16* __restrict__ act3) {
  const int g = blockIdx.x * 256 + threadIdx.x;  // 4*64*256 = 65536
  const int co8 = g & 255;
  const int rest = g >> 8;
  const int px = rest & 3, py = (rest >> 2) & 3, pz = (rest >> 4) & 3, b = rest >> 6;
  float bv[8];
  #pragma unroll
  for (int i = 0; i < 8; ++i) bv[i] = bias[co8 * 8 + i];
  float mx[8];
  #pragma unroll
  for (int i = 0; i < 8; ++i) mx[i] = 0.f;
  #pragma unroll
  for (int dz = 0; dz < 2; ++dz)
    #pragma unroll
    for (int dy = 0; dy < 2; ++dy)
      #pragma unroll
      for (int dx = 0; dx < 2; ++dx) {
        const int pos = ((2 * pz + dz) * 8 + (2 * py + dy)) * 8 + (2 * px + dx);
        float s[8];
        #pragma unroll
        for (int i = 0; i < 8; ++i) s[i] = bv[i];
        for (int c = 0; c < 4; ++c) {
          const float* p = part + ((size_t)(c * 4 + b) * 512 + pos) * 2048 + co8 * 8;
          const f32x4 v0 = *(const f32x4*)p;
          const f32x4 v1 = *(const f32x4*)(p + 4);
          #pragma unroll
          for (int i = 0; i < 4; ++i) { s[i] += v0[i]; s[4 + i] += v1[i]; }
        }
        #pragma unroll
        for (int i = 0; i < 8; ++i) mx[i] = fmaxf(mx[i], s[i]);
      }
  f16x8 o;
  #pragma unroll
  for (int i = 0; i < 8; ++i) o[i] = (f16)mx[i];
  const size_t d = ((size_t)(b * 6 + pz + 1) * 6 + (py + 1)) * 6 + (px + 1);
  *(f16x8*)&act3[d * 2048 + co8 * 8] = o;
}

// ---------------- conv3 reduce + bias + relu + pool -> l4p[b][8][2048] f32 ---
__global__ __launch_bounds__(256) void k_l4fin(const float* __restrict__ part, const float* __restrict__ bias,
                                               float* __restrict__ l4p) {
  const int co = blockIdx.x * 256 + threadIdx.x;  // 0..2047
  const int pp = blockIdx.y;                      // 0..7
  const int b = blockIdx.z;
  const int pz = (pp >> 2) & 1, py = (pp >> 1) & 1, px = pp & 1;
  const float bv = bias[co];
  float mx = 0.f;  // relu'd values are >= 0
  #pragma unroll
  for (int dz = 0; dz < 2; ++dz)
    #pragma unroll
    for (int dy = 0; dy < 2; ++dy)
      #pragma unroll
      for (int dx = 0; dx < 2; ++dx) {
        const int p = b * 64 + ((pz * 2 + dz) << 4) + ((py * 2 + dy) << 2) + (px * 2 + dx);
        float s = bv;
        for (int tp = 0; tp < 27; ++tp) s += part[((size_t)tp * 256 + p) * 2048 + co];
        mx = fmaxf(mx, fmaxf(s, 0.f));
      }
  l4p[((size_t)b * 8 + pp) * 2048 + co] = mx;
}

// ---------------- linear (EMB=16384 -> 128) ----------------------------------
__global__ __launch_bounds__(256) void k_linear(const float* __restrict__ l4p, const float* __restrict__ lw,
                                                const float* __restrict__ lb, float* __restrict__ y) {
  const int o = blockIdx.x, t = threadIdx.x;
  const float* wr = lw + (size_t)o * 16384;
  float a0 = 0, a1 = 0, a2 = 0, a3 = 0;
  for (int k = t; k < 16384; k += 256) {
    const float wv = wr[k];
    const int co = k >> 3, pp = k & 7;
    a0 += wv * l4p[(size_t)(0 * 8 + pp) * 2048 + co];
    a1 += wv * l4p[(size_t)(1 * 8 + pp) * 2048 + co];
    a2 += wv * l4p[(size_t)(2 * 8 + pp) * 2048 + co];
    a3 += wv * l4p[(size_t)(3 * 8 + pp) * 2048 + co];
  }
  __shared__ float red[4][256];
  red[0][t] = a0; red[1][t] = a1; red[2][t] = a2; red[3][t] = a3;
  __syncthreads();
  if (t < 4) {
    float s = 0.f;
    for (int i = 0; i < 256; ++i) s += red[t][i];
    y[t * 128 + o] = s + lb[o];
  }
}

// ---------------- batchnorm over batch (B=4) ---------------------------------
__global__ void k_bn(const float* __restrict__ y, const float* __restrict__ gamma,
                     const float* __restrict__ beta, float* __restrict__ out) {
  const int o = threadIdx.x;  // 128
  const float v0 = y[o], v1 = y[128 + o], v2 = y[256 + o], v3 = y[384 + o];
  const float mu = 0.25f * (v0 + v1 + v2 + v3);
  const float d0 = v0 - mu, d1 = v1 - mu, d2 = v2 - mu, d3 = v3 - mu;
  const float var = 0.25f * (d0 * d0 + d1 * d1 + d2 * d2 + d3 * d3);
  const float inv = 1.0f / sqrtf(var + 1e-5f);
  const float g = gamma[o], be = beta[o];
  out[o] = g * d0 * inv + be;
  out[128 + o] = g * d1 * inv + be;
  out[256 + o] = g * d2 * inv + be;
  out[384 + o] = g * d3 * inv + be;
}

extern "C" void kernel_launch(void* const* d_in, const int* in_sizes, int n_in,
                              void* d_out, int out_size, void* d_ws, size_t ws_size,
                              hipStream_t stream) {
  (void)in_sizes; (void)n_in; (void)out_size; (void)ws_size;
  const float* scene = (const float*)d_in[0];
  const float* pw0 = (const float*)d_in[1];
  const float* pb0 = (const float*)d_in[2];
  const float* pw1 = (const float*)d_in[3];
  const float* pb1 = (const float*)d_in[4];
  const float* cw0 = (const float*)d_in[5];
  const float* cb0 = (const float*)d_in[6];
  const float* cw1 = (const float*)d_in[7];
  const float* cb1 = (const float*)d_in[8];
  const float* cw2 = (const float*)d_in[9];
  const float* cb2 = (const float*)d_in[10];
  const float* cw3 = (const float*)d_in[11];
  const float* cb3 = (const float*)d_in[12];
  const float* lw = (const float*)d_in[13];
  const float* lb = (const float*)d_in[14];
  const float* gm = (const float*)d_in[15];
  const float* bt = (const float*)d_in[16];

  char* ws = (char*)d_ws;
  size_t off = 0;
  auto alloc = [&](size_t bytes) -> char* {
    char* p = ws + off;
    off += (bytes + 255) & ~(size_t)255;
    return p;
  };
  f16* wt0 = (f16*)alloc((size_t)27 * 512 * 256 * 2);
  f16* wt1 = (f16*)alloc((size_t)27 * 1024 * 512 * 2);
  f16* wt2 = (f16*)alloc((size_t)27 * 2048 * 1024 * 2);
  f16* A3  = (f16*)alloc((size_t)256 * 55296 * 2);          // 28.3 MiB im2col
  char* arenaA = alloc((size_t)4 * 32768 * 256 * 4);        // 128 MiB
  char* arenaB = alloc((size_t)4 * 34 * 34 * 34 * 256 * 2); // 76.8 MiB
  f16* act1 = (f16*)alloc((size_t)4 * 18 * 18 * 18 * 512 * 2);
  f16* act2 = (f16*)alloc((size_t)4 * 10 * 10 * 10 * 1024 * 2);
  f16* act3 = (f16*)alloc((size_t)4 * 6 * 6 * 6 * 2048 * 2);
  float* l4p = (float*)alloc((size_t)4 * 8 * 2048 * 4);
  float* ybuf = (float*)alloc(512 * 4);

  float* vox = (float*)arenaA;              // live: mlp..pack
  float* part3 = (float*)arenaA;            // live: conv3c..l4fin (vox dead), 56.6 MB
  f16* act0 = (f16*)arenaB;                 // live: pack..conv0
  float* part2 = (float*)arenaB;            // live: conv2..red2pool (act0 dead), 67.1 MB

  hipMemsetAsync(vox, 0, (size_t)4 * 32768 * 256 * 4, stream);
  hipMemsetAsync(act0, 0, (size_t)4 * 34 * 34 * 34 * 256 * 2, stream);
  hipMemsetAsync(act1, 0, (size_t)4 * 18 * 18 * 18 * 512 * 2, stream);
  hipMemsetAsync(act2, 0, (size_t)4 * 10 * 10 * 10 * 1024 * 2, stream);
  hipMemsetAsync(act3, 0, (size_t)4 * 6 * 6 * 6 * 2048 * 2, stream);

  k_wcast2<<<256, 256, 0, stream>>>(cw0, wt0, 512 * 256);
  k_wcast2<<<1024, 256, 0, stream>>>(cw1, wt1, 1024 * 512);
  k_wcast2<<<4096, 256, 0, stream>>>(cw2, wt2, 2048 * 1024);
  // cw3 consumed directly by k_conv3c (no cast pass)

  k_mlp<<<2048, 256, 0, stream>>>(scene, pw0, pb0, pw1, pb1, vox);
  k_pack<<<16384, 256, 0, stream>>>(vox, act0);

  // conv0/conv1: fused bias+relu+maxpool epilogue (pool kernels eliminated)
  k_conv5<256, 512, 32, 2, 8, 16, 1, false, true><<<dim3(128, 2, 4), 512, 0, stream>>>(act0, wt0, cb0, act1);
  k_conv5<512, 1024, 16, 2, 8, 16, 1, false, true><<<dim3(16, 4, 4), 512, 0, stream>>>(act1, wt1, cb1, act2);

  // conv2: K-split f32 partials + fused reduce/pool
  k_conv5<1024, 2048, 8, 4, 8, 8, 4, true, false><<<dim3(2, 32, 4), 512, 0, stream>>>(act2, wt2, nullptr, part2);
  k_red2pool<<<256, 256, 0, stream>>>(part2, cb2, act3);

  // conv3: im2col + direct-f32-weight GEMM
  k_im2col<<<2048, 256, 0, stream>>>(act3, A3);
  k_conv3c<<<dim3(8, 27), 512, 0, stream>>>(A3, cw3, part3);
  k_l4fin<<<dim3(8, 8, 4), 256, 0, stream>>>(part3, cb3, l4p);

  k_linear<<<128, 256, 0, stream>>>(l4p, lw, lb, ybuf);
  k_bn<<<1, 128, 0, stream>>>(ybuf, gm, bt, (float*)d_out);
}

// Round 12
// 1847.307 us; speedup vs baseline: 1.1643x; 1.0136x over previous
//
#include <hip/hip_runtime.h>
#include <cstdint>
#include <cstddef>

using f16 = _Float16;
typedef __attribute__((ext_vector_type(2))) _Float16 f16x2;
typedef __attribute__((ext_vector_type(4))) _Float16 f16x4;
typedef __attribute__((ext_vector_type(8))) _Float16 f16x8;
typedef __attribute__((ext_vector_type(4))) float f32x4;

#define DEV __device__ __forceinline__

DEV void gload16(const f16* g, f16* l) {
  __builtin_amdgcn_global_load_lds(
      (const __attribute__((address_space(1))) unsigned int*)g,
      (__attribute__((address_space(3))) unsigned int*)l, 16, 0, 0);
}

// ---------------- zero only the pad border of [4][Q][Q][Q][C] f16 ------------
template<int C, int Q>
__global__ __launch_bounds__(256) void k_zborder(f16* __restrict__ a) {
  constexpr int CG = C / 8;
  const size_t g = (size_t)blockIdx.x * 256 + threadIdx.x;  // 4*Q^3*CG
  const int cg = (int)(g % CG);
  size_t r = g / CG;
  const int x = (int)(r % Q); r /= Q;
  const int y = (int)(r % Q); r /= Q;
  const int z = (int)(r % Q);
  const int b = (int)(r / Q);
  if (b >= 4) return;
  const bool border = (x == 0) | (x == Q - 1) | (y == 0) | (y == Q - 1) |
                      (z == 0) | (z == Q - 1);
  if (!border) return;
  f16x8 zz = {};
  *(f16x8*)(a + ((size_t)((b * Q + z) * Q + y) * Q + x) * C + cg * 8) = zz;
}

// ------- weight transform: [co][ci][27] f32 -> [tap][co*ci] f16, f16x2 stores
__global__ __launch_bounds__(256) void k_wcast2(const float* __restrict__ W,
                                                f16* __restrict__ out, int total) {
  __shared__ float raw[256 * 55];  // 512 pos, pair-padded (2*27+1)
  const int t = threadIdx.x;
  const size_t pb = (size_t)blockIdx.x * 512;
  const float* src = W + pb * 27;
  for (int i = t; i < 512 * 27; i += 256) {
    const int pos = i / 27, tap = i - pos * 27;
    raw[(pos >> 1) * 55 + (pos & 1) * 27 + tap] = src[i];
  }
  __syncthreads();
  #pragma unroll
  for (int tap = 0; tap < 27; ++tap) {
    f16x2 v;
    v[0] = (f16)raw[t * 55 + tap];
    v[1] = (f16)raw[t * 55 + 27 + tap];
    *(f16x2*)(out + (size_t)tap * total + pb + t * 2) = v;
  }
}

// ---------------- point MLP + scatter-max into vox[b][32768][256] f32 --------
__global__ __launch_bounds__(256) void k_mlp(const float* __restrict__ pc,
    const float* __restrict__ w0, const float* __restrict__ b0,
    const float* __restrict__ w1, const float* __restrict__ b1,
    float* __restrict__ vox) {
  __shared__ float s_x[64][9];
  __shared__ int s_flat[64];
  __shared__ float s_w0[128 * 9];
  __shared__ float s_b0[128];
  __shared__ float s_b1[256];
  __shared__ __align__(16) f16 s_h0[64 * 128];
  const int t = threadIdx.x;
  const int pt0 = blockIdx.x * 64;
  const int b = pt0 >> 15;
  for (int i = t; i < 128 * 9; i += 256) s_w0[i] = w0[i];
  if (t < 128) s_b0[t] = b0[t];
  if (t >= 128) s_b1[t - 128] = b1[t - 128];
  if (t < 128) s_b1[t + 128] = b1[t + 128];
  if (t < 64) {
    const float* p = pc + (size_t)(pt0 + t) * 6;
    float x = p[0], y = p[1], z = p[2];
    int ix = (int)floorf(x * 32.f), iy = (int)floorf(y * 32.f), iz = (int)floorf(z * 32.f);
    float cx = (ix + 0.5f) * 0.03125f, cy = (iy + 0.5f) * 0.03125f, cz = (iz + 0.5f) * 0.03125f;
    s_x[t][0] = x - cx; s_x[t][1] = y - cy; s_x[t][2] = z - cz;
    s_x[t][3] = cx; s_x[t][4] = cy; s_x[t][5] = cz;
    s_x[t][6] = p[3]; s_x[t][7] = p[4]; s_x[t][8] = p[5];
    s_flat[t] = (ix * 32 + iy) * 32 + iz;
  }
  __syncthreads();
  {
    const int pt = t >> 2, o0 = (t & 3) * 32;
    float xr[9];
    #pragma unroll
    for (int i = 0; i < 9; ++i) xr[i] = s_x[pt][i];
    for (int j = 0; j < 32; ++j) {
      const int o = o0 + j;
      float s = s_b0[o];
      #pragma unroll
      for (int i = 0; i < 9; ++i) s += xr[i] * s_w0[o * 9 + i];
      s_h0[pt * 128 + o] = (f16)fmaxf(s, 0.f);
    }
  }
  __syncthreads();
  const int l = t & 63, w = t >> 6;
  const int co0 = w * 64;
  f32x4 acc[4][4] = {};
  #pragma unroll
  for (int kc = 0; kc < 4; ++kc) {
    f16x8 af[4], bf[4];
    #pragma unroll
    for (int mf = 0; mf < 4; ++mf)
      af[mf] = *(const f16x8*)&s_h0[(mf * 16 + (l & 15)) * 128 + kc * 32 + (l >> 4) * 8];
    #pragma unroll
    for (int nf = 0; nf < 4; ++nf) {
      const float* wr = w1 + (size_t)(co0 + nf * 16 + (l & 15)) * 128 + kc * 32 + (l >> 4) * 8;
      f16x8 v;
      #pragma unroll
      for (int i = 0; i < 8; ++i) v[i] = (f16)wr[i];
      bf[nf] = v;
    }
    #pragma unroll
    for (int mf = 0; mf < 4; ++mf)
      #pragma unroll
      for (int nf = 0; nf < 4; ++nf)
        acc[mf][nf] = __builtin_amdgcn_mfma_f32_16x16x32_f16(af[mf], bf[nf], acc[mf][nf], 0, 0, 0);
  }
  unsigned int* vb = (unsigned int*)vox + (size_t)b * 32768 * 256;
  #pragma unroll
  for (int mf = 0; mf < 4; ++mf) {
    #pragma unroll
    for (int r = 0; r < 4; ++r) {
      const int prow = mf * 16 + (l >> 4) * 4 + r;
      const int fl = s_flat[prow];
      #pragma unroll
      for (int nf = 0; nf < 4; ++nf) {
        const int co = co0 + nf * 16 + (l & 15);
        float v = fmaxf(acc[mf][nf][r] + s_b1[co], 0.f);
        atomicMax(&vb[(size_t)fl * 256 + co], __float_as_uint(v));
      }
    }
  }
}

// ---------------- vox f32 -> padded act0 f16 [b][34][34][34][256] ------------
__global__ __launch_bounds__(256) void k_pack(const float* __restrict__ vox, f16* __restrict__ act0) {
  const size_t g = (size_t)blockIdx.x * 256 + threadIdx.x;  // B*32768*32
  const int cg = (int)(g & 31);
  const size_t bv = g >> 5;
  const int v = (int)(bv & 32767);
  const int b = (int)(bv >> 15);
  const int ix = v >> 10, iy = (v >> 5) & 31, iz = v & 31;
  const float* src = vox + bv * 256 + (size_t)cg * 8;
  f16x8 h;
  #pragma unroll
  for (int i = 0; i < 8; ++i) h[i] = (f16)src[i];
  const size_t pad = (size_t)b * 34 * 34 * 34 + (size_t)((ix + 1) * 34 + (iy + 1)) * 34 + (iz + 1);
  *(f16x8*)(act0 + pad * 256 + cg * 8) = h;
}

// ---------------- 8-wave 4-buffer conv3d, 2-phase consume, counted lgkmcnt ---
// act: [b][S+2][S+2][S+2][CIN] f16 padded ; wt: [27][COUT][CIN] f16
// POOL: fused bias+relu+maxpool2 epilogue -> padded [b][S/2+2]^3[COUT] f16.
template<int CIN, int COUT, int S, int TZ, int TY, int TX, int KSPLIT, bool F32OUT, bool POOL>
__global__ __launch_bounds__(512, 2) void k_conv5(
    const f16* __restrict__ act, const f16* __restrict__ wt,
    const float* __restrict__ bias, void* __restrict__ outp) {
  constexpr int SP = S + 2;
  constexpr int CHK = CIN / KSPLIT;
  constexpr int HC = CHK / 32;             // 32-ci halves per tap
  constexpr int NH = 27 * HC;
  constexpr int NXT = S / TX, NYT = S / TY;
  constexpr int NTILES = COUT / 256;
  static_assert(TZ * TY * TX == 256, "M tile must be 256");
  static_assert((HC & (HC - 1)) == 0, "HC pow2");
  static_assert(!POOL || (!(TZ & 1) && !(TY & 1) && !(TX & 1)), "POOL needs even tile dims");
  __shared__ __align__(16) f16 sm[4 * 16384];  // 128 KiB: [buf][A 16K | B 16K]

  const int t = threadIdx.x, l = t & 63, w = t >> 6;
  const int b = blockIdx.z;
  const int ny = blockIdx.y % NTILES;
  const int chunk = blockIdx.y / NTILES;
  const int co0 = ny * 256;
  int mt = blockIdx.x;
  const int x0 = (mt % NXT) * TX; mt /= NXT;
  const int y0 = (mt % NYT) * TY; mt /= NYT;
  const int z0 = mt * TZ;

  const int u = (l & 7) ^ ((l >> 3) & 7);
  const int kun = (u & 3) * 8;
  uint32_t aoff[2], boff[2];
  #pragma unroll
  for (int j = 0; j < 2; ++j) {
    const int row = j * 64 + w * 8 + (l >> 3);   // 0..127
    const int pos = row * 2 + (u >> 2);          // 0..255
    const int tz = pos / (TY * TX), ty = (pos / TX) % TY, tx = pos % TX;
    aoff[j] = (uint32_t)b * (SP * SP * SP * CIN)
            + (uint32_t)(((z0 + tz) * SP + (y0 + ty)) * SP + (x0 + tx)) * CIN
            + (uint32_t)chunk * CHK + kun;
    boff[j] = (uint32_t)(co0 + pos) * CIN + (uint32_t)chunk * CHK + kun;
  }
  const int ldsw = w * 512;

  auto stage = [&](int nbuf, uint32_t sA, uint32_t sB) {
    f16* base = &sm[nbuf * 16384];
    gload16(act + aoff[0] + sA, base + ldsw);
    gload16(act + aoff[1] + sA, base + 4096 + ldsw);
    gload16(wt + boff[0] + sB, base + 8192 + ldsw);
    gload16(wt + boff[1] + sB, base + 12288 + ldsw);
  };

  int kc_ = 0, kw_ = 0, kh_ = 0, kd_ = 0;
  auto nextAB = [&](uint32_t& sA, uint32_t& sB) {
    sA = (uint32_t)(((kd_ * SP + kh_) * SP + kw_) * CIN) + (uint32_t)kc_ * 32;
    sB = (uint32_t)((kd_ * 3 + kh_) * 3 + kw_) * (uint32_t)(COUT * CIN) + (uint32_t)kc_ * 32;
    if (++kc_ == HC) { kc_ = 0; if (++kw_ == 3) { kw_ = 0; if (++kh_ == 3) { kh_ = 0; ++kd_; } } }
  };

  {
    uint32_t sA, sB;
    nextAB(sA, sB); stage(0, sA, sB);
    nextAB(sA, sB); stage(1, sA, sB);
    nextAB(sA, sB); stage(2, sA, sB);
  }

  const int m0 = (w >> 2) * 128, n0 = (w & 3) * 64;
  const int c0 = l >> 4;
  const int slot = (((l & 1) << 2) | c0) ^ ((l >> 1) & 7);
  const int aidx0 = (m0 / 2 + ((l & 15) >> 1)) * 64 + slot * 8;
  const int bidx0 = 8192 + (n0 / 2 + ((l & 15) >> 1)) * 64 + slot * 8;

  f32x4 acc[8][4] = {};

  auto consume = [&](int buf, bool dostage) {
    const int B0 = buf * 16384;
    f16x8 af0[4], af1[4], bf[4];
    #pragma unroll
    for (int mf = 0; mf < 4; ++mf) af0[mf] = *(const f16x8*)&sm[B0 + aidx0 + mf * 512];
    #pragma unroll
    for (int nf = 0; nf < 4; ++nf) bf[nf] = *(const f16x8*)&sm[B0 + bidx0 + nf * 512];
    __builtin_amdgcn_sched_barrier(0);
    #pragma unroll
    for (int mf = 0; mf < 4; ++mf) af1[mf] = *(const f16x8*)&sm[B0 + aidx0 + (4 + mf) * 512];
    if (dostage) { uint32_t sA, sB; nextAB(sA, sB); stage((buf + 3) & 3, sA, sB); }
    __builtin_amdgcn_sched_barrier(0);
    asm volatile("s_waitcnt lgkmcnt(4)" ::: "memory");
    __builtin_amdgcn_sched_barrier(0);
    __builtin_amdgcn_s_setprio(1);
    #pragma unroll
    for (int mf = 0; mf < 4; ++mf)
      #pragma unroll
      for (int nf = 0; nf < 4; ++nf)
        acc[mf][nf] = __builtin_amdgcn_mfma_f32_16x16x32_f16(af0[mf], bf[nf], acc[mf][nf], 0, 0, 0);
    __builtin_amdgcn_s_setprio(0);
    __builtin_amdgcn_sched_barrier(0);
    asm volatile("s_waitcnt lgkmcnt(0)" ::: "memory");
    __builtin_amdgcn_sched_barrier(0);
    __builtin_amdgcn_s_setprio(1);
    #pragma unroll
    for (int mf = 0; mf < 4; ++mf)
      #pragma unroll
      for (int nf = 0; nf < 4; ++nf)
        acc[4 + mf][nf] = __builtin_amdgcn_mfma_f32_16x16x32_f16(af1[mf], bf[nf], acc[4 + mf][nf], 0, 0, 0);
    __builtin_amdgcn_s_setprio(0);
    __builtin_amdgcn_sched_barrier(0);
  };

  #pragma unroll 4
  for (int h = 0; h < NH - 3; ++h) {
    asm volatile("s_waitcnt vmcnt(8)" ::: "memory");
    __builtin_amdgcn_s_barrier();
    consume(h & 3, true);
  }
  asm volatile("s_waitcnt vmcnt(8)" ::: "memory");
  __builtin_amdgcn_s_barrier();
  consume((NH - 3) & 3, false);
  asm volatile("s_waitcnt vmcnt(4)" ::: "memory");
  __builtin_amdgcn_s_barrier();
  consume((NH - 2) & 3, false);
  asm volatile("s_waitcnt vmcnt(0)" ::: "memory");
  __builtin_amdgcn_s_barrier();
  consume((NH - 1) & 3, false);

  // --- epilogue ---
  if constexpr (POOL) {
    __builtin_amdgcn_s_barrier();
    // phase 1: relu'd tile -> LDS [co 256][pos 256] f16, 16B-unit XOR swizzle
    const int lco_ = n0 + (l & 15);
    #pragma unroll
    for (int nf = 0; nf < 4; ++nf) {
      const int co = lco_ + nf * 16;
      const float brv = bias[co0 + co];
      const int swz = (((co & 15) ^ ((co >> 4) & 15)) & 15) << 4;
      #pragma unroll
      for (int mf = 0; mf < 8; ++mf) {
        const int p = m0 + mf * 16 + (l >> 4) * 4;
        f16x4 v;
        #pragma unroll
        for (int r = 0; r < 4; ++r) v[r] = (f16)fmaxf(acc[mf][nf][r] + brv, 0.f);
        *(f16x4*)((char*)sm + co * 512 + ((p * 2) ^ swz)) = v;
      }
    }
    asm volatile("s_waitcnt lgkmcnt(0)" ::: "memory");
    __builtin_amdgcn_s_barrier();
    // phase 2: 2x2x2 max, vectorized global store
    constexpr int PY = TY / 2, PX = TX / 2;
    const int q = t >> 4;
    const int cs = (t & 15) * 16;
    const int qz = q / (PY * PX), qy = (q / PX) % PY, qx = q % PX;
    f16x8 o0, o1;
    #pragma unroll
    for (int i = 0; i < 16; ++i) {
      const int co = cs + i;
      const int swz = (((co & 15) ^ ((co >> 4) & 15)) & 15) << 4;
      float m = 0.f;
      #pragma unroll
      for (int dz = 0; dz < 2; ++dz)
        #pragma unroll
        for (int dy = 0; dy < 2; ++dy) {
          const int p = (2 * qz + dz) * (TY * TX) + (2 * qy + dy) * TX + 2 * qx;
          const f16x2 pr = *(const f16x2*)((const char*)sm + co * 512 + ((p * 2) ^ swz));
          m = fmaxf(m, fmaxf((float)pr[0], (float)pr[1]));
        }
      if (i < 8) o0[i] = (f16)m; else o1[i - 8] = (f16)m;
    }
    constexpr int Q = S / 2 + 2;
    const int gz = (z0 >> 1) + qz + 1, gy = (y0 >> 1) + qy + 1, gx = (x0 >> 1) + qx + 1;
    f16* dst = (f16*)outp + ((size_t)b * Q * Q * Q + (size_t)(gz * Q + gy) * Q + gx) * COUT + co0 + cs;
    *(f16x8*)dst = o0;
    *(f16x8*)(dst + 8) = o1;
  } else if constexpr (!F32OUT) {
    f16* pp = (f16*)outp;
    float br[4];
    #pragma unroll
    for (int nf = 0; nf < 4; ++nf) br[nf] = bias[co0 + n0 + nf * 16 + (l & 15)];
    const size_t ppb = (size_t)b * (S * S * S) * COUT;
    #pragma unroll
    for (int mf = 0; mf < 8; ++mf) {
      #pragma unroll
      for (int r = 0; r < 4; ++r) {
        const int p = m0 + mf * 16 + (l >> 4) * 4 + r;
        const int tz = p / (TY * TX), ty = (p / TX) % TY, tx = p % TX;
        const size_t row = ppb + (size_t)(((z0 + tz) * S + (y0 + ty)) * S + (x0 + tx)) * COUT;
        #pragma unroll
        for (int nf = 0; nf < 4; ++nf)
          pp[row + co0 + n0 + nf * 16 + (l & 15)] = (f16)fmaxf(acc[mf][nf][r] + br[nf], 0.f);
      }
    }
  } else {
    float* part = (float*)outp;
    const size_t base = ((size_t)chunk * 4 + b) * (S * S * S);
    #pragma unroll
    for (int mf = 0; mf < 8; ++mf) {
      #pragma unroll
      for (int r = 0; r < 4; ++r) {
        const int p = m0 + mf * 16 + (l >> 4) * 4 + r;
        const int tz = p / (TY * TX), ty = (p / TX) % TY, tx = p % TX;
        const int pos = ((z0 + tz) * S + (y0 + ty)) * S + (x0 + tx);
        #pragma unroll
        for (int nf = 0; nf < 4; ++nf)
          part[(base + pos) * COUT + co0 + n0 + nf * 16 + (l & 15)] = acc[mf][nf][r];
      }
    }
  }
}

// ---------------- im2col for conv3: act3 -> A3[256 pos][55296 K] f16 ---------
__global__ __launch_bounds__(256) void k_im2col(const f16* __restrict__ act3,
                                                f16* __restrict__ A3) {
  const int g = blockIdx.x * 256 + threadIdx.x;  // 256*2048 = 524288
  const int ci = g & 2047;
  const int pos = g >> 11;
  const int b = pos >> 6, c = pos & 63;
  const int tz = c >> 4, ty = (c >> 2) & 3, tx = c & 3;
  f16* dst = A3 + (size_t)pos * 55296 + ci * 27;
  #pragma unroll
  for (int kd = 0; kd < 3; ++kd)
    #pragma unroll
    for (int kh = 0; kh < 3; ++kh)
      #pragma unroll
      for (int kw = 0; kw < 3; ++kw)
        dst[(kd * 3 + kh) * 3 + kw] =
            act3[(size_t)((b * 216 + (tz + kd) * 36 + (ty + kh) * 6 + (tx + kw)) * 2048) + ci];
}

// ---------------- conv3c: GEMM 256x2048 @ K=55296, B direct from f32 weights -
__global__ __launch_bounds__(512, 2) void k_conv3c(const f16* __restrict__ A3,
    const float* __restrict__ W, float* __restrict__ part) {
  __shared__ __align__(16) f16 sm[4 * 16384];
  const int t = threadIdx.x, l = t & 63, w = t >> 6;
  const int co0 = blockIdx.x * 256;
  const int chunk = blockIdx.y;
  const uint32_t kb0 = (uint32_t)chunk * 2048;

  const int u = (l & 7) ^ ((l >> 3) & 7);
  const int kun = (u & 3) * 8;
  uint32_t aoff[2];
  const float* wrow[2];
  #pragma unroll
  for (int j = 0; j < 2; ++j) {
    const int row = j * 64 + w * 8 + (l >> 3);
    const int pos = row * 2 + (u >> 2);
    aoff[j] = (uint32_t)pos * 55296u + kb0 + kun;
    wrow[j] = W + (size_t)(co0 + pos) * 55296 + kb0 + kun;
  }
  const int ldsw = w * 512;

  auto stageA = [&](int nbuf, uint32_t s) {
    f16* base = &sm[nbuf * 16384];
    gload16(A3 + aoff[0] + s, base + ldsw);
    gload16(A3 + aoff[1] + s, base + 4096 + ldsw);
  };
  f32x4 bregA[4], bregB[4];
  auto loadB = [&](f32x4 (&bs)[4], uint32_t s) {
    bs[0] = *(const f32x4*)(wrow[0] + s);
    bs[1] = *(const f32x4*)(wrow[0] + s + 4);
    bs[2] = *(const f32x4*)(wrow[1] + s);
    bs[3] = *(const f32x4*)(wrow[1] + s + 4);
  };
  auto writeB = [&](int nbuf, const f32x4 (&bs)[4]) {
    f16* base = &sm[nbuf * 16384 + 8192 + ldsw + l * 8];
    f16x8 v0, v1;
    #pragma unroll
    for (int i = 0; i < 4; ++i) {
      v0[i] = (f16)bs[0][i]; v0[4 + i] = (f16)bs[1][i];
      v1[i] = (f16)bs[2][i]; v1[4 + i] = (f16)bs[3][i];
    }
    *(f16x8*)(base) = v0;
    *(f16x8*)(base + 4096) = v1;
  };

  const int m0 = (w >> 2) * 128, n0 = (w & 3) * 64;
  const int c0 = l >> 4;
  const int slot = (((l & 1) << 2) | c0) ^ ((l >> 1) & 7);
  const int aidx0 = (m0 / 2 + ((l & 15) >> 1)) * 64 + slot * 8;
  const int bidx0 = 8192 + (n0 / 2 + ((l & 15) >> 1)) * 64 + slot * 8;

  f32x4 acc[8][4] = {};

  auto consume = [&](int buf, f32x4 (&bs)[4], int hn, bool dowrite) {
    if (dowrite) writeB((buf + 1) & 3, bs);
    __builtin_amdgcn_s_barrier();
    const int B0 = buf * 16384;
    f16x8 af0[4], af1[4], bf[4];
    #pragma unroll
    for (int mf = 0; mf < 4; ++mf) af0[mf] = *(const f16x8*)&sm[B0 + aidx0 + mf * 512];
    #pragma unroll
    for (int nf = 0; nf < 4; ++nf) bf[nf] = *(const f16x8*)&sm[B0 + bidx0 + nf * 512];
    __builtin_amdgcn_sched_barrier(0);
    #pragma unroll
    for (int mf = 0; mf < 4; ++mf) af1[mf] = *(const f16x8*)&sm[B0 + aidx0 + (4 + mf) * 512];
    if (hn >= 0) { loadB(bs, (uint32_t)hn * 32u); stageA(hn & 3, (uint32_t)hn * 32u); }
    __builtin_amdgcn_sched_barrier(0);
    asm volatile("s_waitcnt lgkmcnt(4)" ::: "memory");
    __builtin_amdgcn_sched_barrier(0);
    __builtin_amdgcn_s_setprio(1);
    #pragma unroll
    for (int mf = 0; mf < 4; ++mf)
      #pragma unroll
      for (int nf = 0; nf < 4; ++nf)
        acc[mf][nf] = __builtin_amdgcn_mfma_f32_16x16x32_f16(af0[mf], bf[nf], acc[mf][nf], 0, 0, 0);
    __builtin_amdgcn_s_setprio(0);
    __builtin_amdgcn_sched_barrier(0);
    asm volatile("s_waitcnt lgkmcnt(0)" ::: "memory");
    __builtin_amdgcn_sched_barrier(0);
    __builtin_amdgcn_s_setprio(1);
    #pragma unroll
    for (int mf = 0; mf < 4; ++mf)
      #pragma unroll
      for (int nf = 0; nf < 4; ++nf)
        acc[4 + mf][nf] = __builtin_amdgcn_mfma_f32_16x16x32_f16(af1[mf], bf[nf], acc[4 + mf][nf], 0, 0, 0);
    __builtin_amdgcn_s_setprio(0);
    __builtin_amdgcn_sched_barrier(0);
  };

  loadB(bregA, 0);
  asm volatile("s_waitcnt vmcnt(0)" ::: "memory");
  writeB(0, bregA);
  loadB(bregB, 32);
  loadB(bregA, 64);
  stageA(0, 0); stageA(1, 32); stageA(2, 64);
  asm volatile("s_waitcnt lgkmcnt(0)" ::: "memory");
  __builtin_amdgcn_sched_barrier(0);

  asm volatile("s_waitcnt vmcnt(4)" ::: "memory");
  consume(0, bregB, 3, true);
  #pragma unroll 2
  for (int h = 1; h + 1 <= 60; h += 2) {
    asm volatile("s_waitcnt vmcnt(8)" ::: "memory");
    consume(h & 3, bregA, h + 3, true);
    asm volatile("s_waitcnt vmcnt(8)" ::: "memory");
    consume((h + 1) & 3, bregB, h + 4, true);
  }
  asm volatile("s_waitcnt vmcnt(8)" ::: "memory");
  consume(61 & 3, bregA, -1, true);
  asm volatile("s_waitcnt vmcnt(2)" ::: "memory");
  consume(62 & 3, bregB, -1, true);
  asm volatile("s_waitcnt vmcnt(0)" ::: "memory");
  consume(63 & 3, bregA, -1, false);

  const size_t base = (size_t)chunk * 256 * 2048;
  #pragma unroll
  for (int mf = 0; mf < 8; ++mf) {
    #pragma unroll
    for (int r = 0; r < 4; ++r) {
      const int p = m0 + mf * 16 + (l >> 4) * 4 + r;
      #pragma unroll
      for (int nf = 0; nf < 4; ++nf)
        part[base + (size_t)p * 2048 + co0 + n0 + nf * 16 + (l & 15)] = acc[mf][nf][r];
    }
  }
}

// ---------------- conv2 K-split reduce + bias + relu + pool -> act3 padded ---
__global__ __launch_bounds__(256) void k_red2pool(const float* __restrict__ part,
    const float* __restrict__ bias, f16* __restrict__ act3) {
  const int g = blockIdx.x * 256 + threadIdx.x;  // 4*64*256 = 65536
  const int co8 = g & 255;
  const int rest = g >> 8;
  const int px = rest & 3, py = (rest >> 2) & 3, pz = (rest >> 4) & 3, b = rest >> 6;
  float bv[8];
  #pragma unroll
  for (int i = 0; i < 8; ++i) bv[i] = bias[co8 * 8 + i];
  float mx[8];
  #pragma unroll
  for (int i = 0; i < 8; ++i) mx[i] = 0.f;
  #pragma unroll
  for (int dz = 0; dz < 2; ++dz)
    #pragma unroll
    for (int dy = 0; dy < 2; ++dy)
      #pragma unroll
      for (int dx = 0; dx < 2; ++dx) {
        const int pos = ((2 * pz + dz) * 8 + (2 * py + dy)) * 8 + (2 * px + dx);
        float s[8];
        #pragma unroll
        for (int i = 0; i < 8; ++i) s[i] = bv[i];
        for (int c = 0; c < 4; ++c) {
          const float* p = part + ((size_t)(c * 4 + b) * 512 + pos) * 2048 + co8 * 8;
          const f32x4 v0 = *(const f32x4*)p;
          const f32x4 v1 = *(const f32x4*)(p + 4);
          #pragma unroll
          for (int i = 0; i < 4; ++i) { s[i] += v0[i]; s[4 + i] += v1[i]; }
        }
        #pragma unroll
        for (int i = 0; i < 8; ++i) mx[i] = fmaxf(mx[i], s[i]);
      }
  f16x8 o;
  #pragma unroll
  for (int i = 0; i < 8; ++i) o[i] = (f16)mx[i];
  const size_t d = ((size_t)(b * 6 + pz + 1) * 6 + (py + 1)) * 6 + (px + 1);
  *(f16x8*)&act3[d * 2048 + co8 * 8] = o;
}

// ---------------- conv3 reduce + bias + relu + pool -> l4p[b][8][2048] f32 ---
__global__ __launch_bounds__(256) void k_l4fin(const float* __restrict__ part, const float* __restrict__ bias,
                                               float* __restrict__ l4p) {
  const int co = blockIdx.x * 256 + threadIdx.x;  // 0..2047
  const int pp = blockIdx.y;                      // 0..7
  const int b = blockIdx.z;
  const int pz = (pp >> 2) & 1, py = (pp >> 1) & 1, px = pp & 1;
  const float bv = bias[co];
  float mx = 0.f;  // relu'd values are >= 0
  #pragma unroll
  for (int dz = 0; dz < 2; ++dz)
    #pragma unroll
    for (int dy = 0; dy < 2; ++dy)
      #pragma unroll
      for (int dx = 0; dx < 2; ++dx) {
        const int p = b * 64 + ((pz * 2 + dz) << 4) + ((py * 2 + dy) << 2) + (px * 2 + dx);
        float s = bv;
        for (int tp = 0; tp < 27; ++tp) s += part[((size_t)tp * 256 + p) * 2048 + co];
        mx = fmaxf(mx, fmaxf(s, 0.f));
      }
  l4p[((size_t)b * 8 + pp) * 2048 + co] = mx;
}

// ---------------- linear (EMB=16384 -> 128) + fused batchnorm (B=4) ----------
__global__ __launch_bounds__(256) void k_linear(const float* __restrict__ l4p, const float* __restrict__ lw,
                                                const float* __restrict__ lb,
                                                const float* __restrict__ gamma,
                                                const float* __restrict__ beta,
                                                float* __restrict__ out) {
  const int o = blockIdx.x, t = threadIdx.x;
  const float* wr = lw + (size_t)o * 16384;
  float a0 = 0, a1 = 0, a2 = 0, a3 = 0;
  for (int k = t; k < 16384; k += 256) {
    const float wv = wr[k];
    const int co = k >> 3, pp = k & 7;
    a0 += wv * l4p[(size_t)(0 * 8 + pp) * 2048 + co];
    a1 += wv * l4p[(size_t)(1 * 8 + pp) * 2048 + co];
    a2 += wv * l4p[(size_t)(2 * 8 + pp) * 2048 + co];
    a3 += wv * l4p[(size_t)(3 * 8 + pp) * 2048 + co];
  }
  __shared__ float red[4][256];
  red[0][t] = a0; red[1][t] = a1; red[2][t] = a2; red[3][t] = a3;
  __syncthreads();
  __shared__ float ys[4];
  if (t < 4) {
    float s = 0.f;
    for (int i = 0; i < 256; ++i) s += red[t][i];
    ys[t] = s + lb[o];
  }
  __syncthreads();
  if (t == 0) {
    const float v0 = ys[0], v1 = ys[1], v2 = ys[2], v3 = ys[3];
    const float mu = 0.25f * (v0 + v1 + v2 + v3);
    const float d0 = v0 - mu, d1 = v1 - mu, d2 = v2 - mu, d3 = v3 - mu;
    const float var = 0.25f * (d0 * d0 + d1 * d1 + d2 * d2 + d3 * d3);
    const float inv = 1.0f / sqrtf(var + 1e-5f);
    const float g = gamma[o], be = beta[o];
    out[o] = g * d0 * inv + be;
    out[128 + o] = g * d1 * inv + be;
    out[256 + o] = g * d2 * inv + be;
    out[384 + o] = g * d3 * inv + be;
  }
}

extern "C" void kernel_launch(void* const* d_in, const int* in_sizes, int n_in,
                              void* d_out, int out_size, void* d_ws, size_t ws_size,
                              hipStream_t stream) {
  (void)in_sizes; (void)n_in; (void)out_size; (void)ws_size;
  const float* scene = (const float*)d_in[0];
  const float* pw0 = (const float*)d_in[1];
  const float* pb0 = (const float*)d_in[2];
  const float* pw1 = (const float*)d_in[3];
  const float* pb1 = (const float*)d_in[4];
  const float* cw0 = (const float*)d_in[5];
  const float* cb0 = (const float*)d_in[6];
  const float* cw1 = (const float*)d_in[7];
  const float* cb1 = (const float*)d_in[8];
  const float* cw2 = (const float*)d_in[9];
  const float* cb2 = (const float*)d_in[10];
  const float* cw3 = (const float*)d_in[11];
  const float* cb3 = (const float*)d_in[12];
  const float* lw = (const float*)d_in[13];
  const float* lb = (const float*)d_in[14];
  const float* gm = (const float*)d_in[15];
  const float* bt = (const float*)d_in[16];

  char* ws = (char*)d_ws;
  size_t off = 0;
  auto alloc = [&](size_t bytes) -> char* {
    char* p = ws + off;
    off += (bytes + 255) & ~(size_t)255;
    return p;
  };
  f16* wt0 = (f16*)alloc((size_t)27 * 512 * 256 * 2);
  f16* wt1 = (f16*)alloc((size_t)27 * 1024 * 512 * 2);
  f16* wt2 = (f16*)alloc((size_t)27 * 2048 * 1024 * 2);
  f16* A3  = (f16*)alloc((size_t)256 * 55296 * 2);          // 28.3 MiB im2col
  char* arenaA = alloc((size_t)4 * 32768 * 256 * 4);        // 128 MiB
  char* arenaB = alloc((size_t)4 * 34 * 34 * 34 * 256 * 2); // 76.8 MiB
  f16* act1 = (f16*)alloc((size_t)4 * 18 * 18 * 18 * 512 * 2);
  f16* act2 = (f16*)alloc((size_t)4 * 10 * 10 * 10 * 1024 * 2);
  f16* act3 = (f16*)alloc((size_t)4 * 6 * 6 * 6 * 2048 * 2);
  float* l4p = (float*)alloc((size_t)4 * 8 * 2048 * 4);

  float* vox = (float*)arenaA;              // live: mlp..pack
  float* part3 = (float*)arenaA;            // live: conv3c..l4fin (vox dead), 56.6 MB
  f16* act0 = (f16*)arenaB;                 // live: pack..conv0
  float* part2 = (float*)arenaB;            // live: conv2..red2pool (act0 dead), 67.1 MB

  hipMemsetAsync(vox, 0, (size_t)4 * 32768 * 256 * 4, stream);
  // padded activations: zero only the pad borders (interiors fully overwritten)
  k_zborder<256, 34><<<(4 * 34 * 34 * 34 * 32 + 255) / 256, 256, 0, stream>>>(act0);
  k_zborder<512, 18><<<(4 * 18 * 18 * 18 * 64 + 255) / 256, 256, 0, stream>>>(act1);
  k_zborder<1024, 10><<<(4 * 10 * 10 * 10 * 128 + 255) / 256, 256, 0, stream>>>(act2);
  k_zborder<2048, 6><<<(4 * 6 * 6 * 6 * 256 + 255) / 256, 256, 0, stream>>>(act3);

  k_wcast2<<<256, 256, 0, stream>>>(cw0, wt0, 512 * 256);
  k_wcast2<<<1024, 256, 0, stream>>>(cw1, wt1, 1024 * 512);
  k_wcast2<<<4096, 256, 0, stream>>>(cw2, wt2, 2048 * 1024);
  // cw3 consumed directly by k_conv3c (no cast pass)

  k_mlp<<<2048, 256, 0, stream>>>(scene, pw0, pb0, pw1, pb1, vox);
  k_pack<<<16384, 256, 0, stream>>>(vox, act0);

  // conv0/conv1: fused bias+relu+maxpool epilogue
  k_conv5<256, 512, 32, 2, 8, 16, 1, false, true><<<dim3(128, 2, 4), 512, 0, stream>>>(act0, wt0, cb0, act1);
  k_conv5<512, 1024, 16, 2, 8, 16, 1, false, true><<<dim3(16, 4, 4), 512, 0, stream>>>(act1, wt1, cb1, act2);

  // conv2: K-split f32 partials + fused reduce/pool
  k_conv5<1024, 2048, 8, 4, 8, 8, 4, true, false><<<dim3(2, 32, 4), 512, 0, stream>>>(act2, wt2, nullptr, part2);
  k_red2pool<<<256, 256, 0, stream>>>(part2, cb2, act3);

  // conv3: im2col + direct-f32-weight GEMM
  k_im2col<<<2048, 256, 0, stream>>>(act3, A3);
  k_conv3c<<<dim3(8, 27), 512, 0, stream>>>(A3, cw3, part3);
  k_l4fin<<<dim3(8, 8, 4), 256, 0, stream>>>(part3, cb3, l4p);

  // linear + fused batchnorm
  k_linear<<<128, 256, 0, stream>>>(l4p, lw, lb, gm, bt, (float*)d_out);
}